// Round 12
// baseline (296.052 us; speedup 1.0000x reference)
//
#include <hip/hip_runtime.h>
#include <hip/hip_bf16.h>
#include <cstdint>

#define N_NODES 10000
#define N_EDGES 160000
#define DIM 512
#define K1 1024
#define NEXP 4

typedef __bf16 bf16_t;
typedef bf16_t bf16x8 __attribute__((ext_vector_type(8)));
typedef float f32x4 __attribute__((ext_vector_type(4)));

#define AS1(p) ((__attribute__((address_space(1))) void*)(p))
#define AS3(p) ((__attribute__((address_space(3))) void*)(p))

#define VMW(N) asm volatile("s_waitcnt vmcnt(" #N ")" ::: "memory")
#define MFMA16(d, a_, b_) d = __builtin_amdgcn_mfma_f32_16x16x32_bf16(a_, b_, d, 0, 0, 0)

// ---------------- gating + x->bf16 + counter zeroing (fused; r9-proven) ---------
__global__ void gate_kernel(const float* __restrict__ x,
                            const float* __restrict__ gw,
                            const float* __restrict__ gb,
                            int* __restrict__ top_idx,
                            float* __restrict__ top_val,
                            bf16_t* __restrict__ acat,
                            int* __restrict__ deg,
                            int* __restrict__ ecnt) {
    const int gid = blockIdx.x * 256 + threadIdx.x;
    if (gid < N_NODES) deg[gid] = 0;
    if (gid < NEXP) ecnt[gid] = 0;

    const int wave = threadIdx.x >> 6;
    const int lane = threadIdx.x & 63;
    const int node = blockIdx.x * 4 + wave;
    if (node >= N_NODES) return;
    const float4* x4 = (const float4*)(x + (size_t)node * DIM);
    const float4* gw4 = (const float4*)gw;
    float4 xa = x4[lane * 2];
    float4 xb = x4[lane * 2 + 1];
    float xv[8] = { xa.x, xa.y, xa.z, xa.w, xb.x, xb.y, xb.z, xb.w };
    float a0 = 0.f, a1 = 0.f, a2 = 0.f, a3 = 0.f;
    #pragma unroll
    for (int c = 0; c < 8; c++) {
        float4 g = gw4[lane * 8 + c];
        a0 += xv[c] * g.x; a1 += xv[c] * g.y; a2 += xv[c] * g.z; a3 += xv[c] * g.w;
    }
    bf16x8 o;
    #pragma unroll
    for (int c = 0; c < 8; c++) o[c] = (bf16_t)xv[c];
    *(bf16x8*)(acat + (size_t)node * K1 + DIM + lane * 8) = o;
    for (int off = 32; off > 0; off >>= 1) {
        a0 += __shfl_xor(a0, off);
        a1 += __shfl_xor(a1, off);
        a2 += __shfl_xor(a2, off);
        a3 += __shfl_xor(a3, off);
    }
    if (lane == 0) {
        float z[4] = { a0 + gb[0], a1 + gb[1], a2 + gb[2], a3 + gb[3] };
        int bi = 0; float bm = z[0];
        for (int e = 1; e < 4; e++) if (z[e] > bm) { bm = z[e]; bi = e; }
        float den = 0.f;
        for (int e = 0; e < 4; e++) den += expf(z[e] - bm);
        top_idx[node] = bi;
        top_val[node] = 1.0f / den;
    }
}

// ---------------- expert bucketing + degree count (fused; r9-proven) ---
__global__ void bucket_deg_kernel(const int* __restrict__ top_idx,
                                  int* __restrict__ ecnt,
                                  int* __restrict__ lists,
                                  const int* __restrict__ dst,
                                  int* __restrict__ deg) {
    const int gi = blockIdx.x * 256 + threadIdx.x;
    if (gi < N_EDGES) atomicAdd(&deg[dst[gi]], 1);

    if (blockIdx.x < 40) {
        __shared__ int lcnt[NEXP];
        __shared__ int base[NEXP];
        const int tid = threadIdx.x;
        if (tid < NEXP) lcnt[tid] = 0;
        __syncthreads();
        const int node = blockIdx.x * 256 + tid;
        int e = 0, rank = 0;
        if (node < N_NODES) {
            e = top_idx[node];
            rank = atomicAdd(&lcnt[e], 1);
        }
        __syncthreads();
        if (tid < NEXP) base[tid] = atomicAdd(&ecnt[tid], lcnt[tid]);
        __syncthreads();
        if (node < N_NODES) lists[e * N_NODES + base[e] + rank] = node;
    }
}

// scan + layer-2 job table (fused; r9-proven)
__global__ void scan_kernel(const int* __restrict__ deg,
                            int* __restrict__ offs,
                            int* __restrict__ cursor,
                            const int* __restrict__ ecnt,
                            int* __restrict__ jobs) {
    __shared__ int wsum[16];
    __shared__ int carrysh;
    const int tid = threadIdx.x;
    const int lane = tid & 63;
    const int wv = tid >> 6;
    if (tid == 0) {
        carrysh = 0;
        int pref = 0;
        for (int e2 = 0; e2 < NEXP; e2++) {
            jobs[e2] = pref;
            pref += (ecnt[e2] + 127) >> 7;
        }
        jobs[4] = pref;
    }
    __syncthreads();
    for (int base = 0; base < N_NODES; base += 1024) {
        int i = base + tid;
        int v = (i < N_NODES) ? deg[i] : 0;
        int s = v;
        #pragma unroll
        for (int off = 1; off < 64; off <<= 1) {
            int t = __shfl_up(s, off);
            if (lane >= off) s += t;
        }
        if (lane == 63) wsum[wv] = s;
        int carry = carrysh;
        __syncthreads();
        if (wv == 0) {
            int w = (lane < 16) ? wsum[lane] : 0;
            #pragma unroll
            for (int off = 1; off < 16; off <<= 1) {
                int t = __shfl_up(w, off);
                if (lane >= off) w += t;
            }
            if (lane < 16) wsum[lane] = w;
        }
        __syncthreads();
        int wbase = (wv > 0) ? wsum[wv - 1] : 0;
        int excl = carry + wbase + s - v;
        if (i < N_NODES) { offs[i] = excl; cursor[i] = excl; }
        int total = wsum[15];
        __syncthreads();
        if (tid == 0) carrysh = carry + total;
        __syncthreads();
    }
    if (tid == 0) offs[N_NODES] = carrysh;
}

// ---------------- CSR fill + weight transpose (fused; r9-proven) ------------
__global__ void fill_wtrans_kernel(const int* __restrict__ src, const int* __restrict__ dst,
                                   int* __restrict__ cursor, int* __restrict__ csr,
                                   const float* __restrict__ w_neigh,
                                   const float* __restrict__ w_self,
                                   bf16_t* __restrict__ Bt) {
    if (blockIdx.x < 625) {
        int i = blockIdx.x * 256 + threadIdx.x;
        if (i < N_EDGES) {
            int d = dst[i];
            int p = atomicAdd(&cursor[d], 1);
            csr[p] = src[i];
        }
    } else {
        __shared__ float tile[32][33];
        const int q = blockIdx.x - 625;
        const int m = q >> 8;
        const bool isSelf = m >= 8;
        const int el = m & 7;
        const float* W = (isSelf ? w_self : w_neigh) + (size_t)el * DIM * DIM;
        const int k0 = (q & 15) * 32;
        const int n0 = ((q >> 4) & 15) * 32;
        const int tx = threadIdx.x & 31, ty = threadIdx.x >> 5;
        for (int r = ty; r < 32; r += 8)
            tile[r][tx] = W[(size_t)(k0 + r) * DIM + n0 + tx];
        __syncthreads();
        for (int r = ty; r < 32; r += 8) {
            int n = n0 + r;
            int k = k0 + tx;
            Bt[((size_t)el * DIM + n) * K1 + (isSelf ? DIM : 0) + k] = (bf16_t)tile[tx][r];
        }
    }
}

// ---------------- agg1: mean of x rows into acat cols 0..511, unroll 8 ----------------
__global__ void agg1_kernel(const int* __restrict__ offs, const int* __restrict__ csr,
                            bf16_t* __restrict__ acat) {
    const int wave = threadIdx.x >> 6;
    const int lane = threadIdx.x & 63;
    const int node = blockIdx.x * 4 + wave;
    if (node >= N_NODES) return;
    const int c0 = lane * 8;
    float s[8] = {0,0,0,0,0,0,0,0};
    int beg = offs[node];
    int end = offs[node + 1];
    int d = end - beg;
    int p = beg;
    for (; p + 8 <= end; p += 8) {
        bf16x8 v[8];
        #pragma unroll
        for (int q = 0; q < 8; q++) {
            int idx = csr[p + q];
            v[q] = *(const bf16x8*)(acat + (size_t)idx * K1 + DIM + c0);
        }
        #pragma unroll
        for (int q = 0; q < 8; q++)
            #pragma unroll
            for (int k = 0; k < 8; k++) s[k] += (float)v[q][k];
    }
    for (; p + 4 <= end; p += 4) {
        bf16x8 v[4];
        #pragma unroll
        for (int q = 0; q < 4; q++) {
            int idx = csr[p + q];
            v[q] = *(const bf16x8*)(acat + (size_t)idx * K1 + DIM + c0);
        }
        #pragma unroll
        for (int q = 0; q < 4; q++)
            #pragma unroll
            for (int k = 0; k < 8; k++) s[k] += (float)v[q][k];
    }
    for (; p < end; p++) {
        int idx = csr[p];
        bf16x8 v0 = *(const bf16x8*)(acat + (size_t)idx * K1 + DIM + c0);
        #pragma unroll
        for (int k = 0; k < 8; k++) s[k] += (float)v0[k];
    }
    float w = d > 0 ? 1.0f / (float)d : 0.0f;
    bf16x8 o;
    #pragma unroll
    for (int k = 0; k < 8; k++) o[k] = (bf16_t)(s[k] * w);
    *(bf16x8*)(acat + (size_t)node * K1 + c0) = o;
}

// ---------------- agg2: selected-expert mean of h1 rows + self copy, unroll 8 ----------------
__global__ void agg2_kernel(const int* __restrict__ offs, const int* __restrict__ csr,
                            const int* __restrict__ top_idx,
                            const bf16_t* __restrict__ h1, bf16_t* __restrict__ acat) {
    const int wave = threadIdx.x >> 6;
    const int lane = threadIdx.x & 63;
    const int node = blockIdx.x * 4 + wave;
    if (node >= N_NODES) return;
    const int c0 = lane * 8;
    const bf16_t* hb = h1 + (size_t)top_idx[node] * N_NODES * DIM;
    float s[8] = {0,0,0,0,0,0,0,0};
    int beg = offs[node];
    int end = offs[node + 1];
    int d = end - beg;
    int p = beg;
    for (; p + 8 <= end; p += 8) {
        bf16x8 v[8];
        #pragma unroll
        for (int q = 0; q < 8; q++) {
            int idx = csr[p + q];
            v[q] = *(const bf16x8*)(hb + (size_t)idx * DIM + c0);
        }
        #pragma unroll
        for (int q = 0; q < 8; q++)
            #pragma unroll
            for (int k = 0; k < 8; k++) s[k] += (float)v[q][k];
    }
    for (; p + 4 <= end; p += 4) {
        bf16x8 v[4];
        #pragma unroll
        for (int q = 0; q < 4; q++) {
            int idx = csr[p + q];
            v[q] = *(const bf16x8*)(hb + (size_t)idx * DIM + c0);
        }
        #pragma unroll
        for (int q = 0; q < 4; q++)
            #pragma unroll
            for (int k = 0; k < 8; k++) s[k] += (float)v[q][k];
    }
    for (; p < end; p++) {
        int idx = csr[p];
        bf16x8 v0 = *(const bf16x8*)(hb + (size_t)idx * DIM + c0);
        #pragma unroll
        for (int k = 0; k < 8; k++) s[k] += (float)v0[k];
    }
    float w = d > 0 ? 1.0f / (float)d : 0.0f;
    bf16x8 o;
    #pragma unroll
    for (int k = 0; k < 8; k++) o[k] = (bf16_t)(s[k] * w);
    *(bf16x8*)(acat + (size_t)node * K1 + c0) = o;
    *(bf16x8*)(acat + (size_t)node * K1 + DIM + c0) = *(const bf16x8*)(hb + (size_t)node * DIM + c0);
}

// ---------------- layer-1 GEMM: 640x128, B-from-global, A-only LDS --------------------
// r12 diagnosis: per-tile cycles ~= LDS-port time (120 KB @ measured 85 B/cyc instr-
// limited) + MFMA time (1552 cyc) SERIALIZED -> ~3990 cyc observed, MfmaUtil 32% =
// 1552/3990 with the matrix pipe saturated while active. B-fragment LDS reads are
// x4-redundant (4 wave-pairs read identical data) = 32 KB of the 120. Fix: load B
// fragments DIRECTLY from global (L2/L3-resident weight panel) into registers —
// byte-identical values (the LDS rotation was only a bank-conflict artifact):
//   bq[j][lane] = Bte[((ntile&3)*128 + wn*64 + j*16 + rfr)*K1 + k0 + cpr*8 ..+8]
// LDS now holds A only (2 x 40 KB buffers, r9-proven depth-1 VMW(0) discipline).
// B-loads issue BEFORE the A-stage calls each tile, so the compiler's automatic
// vmcnt wait for bq (vmcnt(5)) leaves the 5 A-stages of tile t+1 in flight.
__global__ __launch_bounds__(512, 2)
void gemm_l1_kernel(const bf16_t* __restrict__ A,
                    const bf16_t* __restrict__ Bt,
                    const float* __restrict__ bias_all,
                    bf16_t* __restrict__ h1) {
    const int b = blockIdx.x;
    const int xcd = b & 7;
    const int loc = b >> 3;
    const int mtile = xcd * 2 + (loc >> 4);
    const int ntile = loc & 15;
    const int e = ntile >> 2;

    __shared__ __align__(16) bf16_t As[2 * 640 * 32];   // 81920 B, A only

    const int t = threadIdx.x;
    const int lane = t & 63;
    const int wave = t >> 6;
    const int rloc = t >> 2;
    const int cgl = ((t & 3) - ((t >> 3) & 3)) & 3;

    const bf16_t* pA0 = A + (size_t)min(mtile * 640 +   0 + rloc, N_NODES - 1) * K1 + cgl * 8;
    const bf16_t* pA1 = A + (size_t)min(mtile * 640 + 128 + rloc, N_NODES - 1) * K1 + cgl * 8;
    const bf16_t* pA2 = A + (size_t)min(mtile * 640 + 256 + rloc, N_NODES - 1) * K1 + cgl * 8;
    const bf16_t* pA3 = A + (size_t)min(mtile * 640 + 384 + rloc, N_NODES - 1) * K1 + cgl * 8;
    const bf16_t* pA4 = A + (size_t)min(mtile * 640 + 512 + rloc, N_NODES - 1) * K1 + cgl * 8;

    char* asb = (char*)&As[0];

    auto stage = [&](int bu) {
        char* ab = asb + bu * 40960 + wave * 1024;
        __builtin_amdgcn_global_load_lds(AS1(pA0), AS3(ab),          16, 0, 0);
        __builtin_amdgcn_global_load_lds(AS1(pA1), AS3(ab + 8192),   16, 0, 0);
        __builtin_amdgcn_global_load_lds(AS1(pA2), AS3(ab + 16384),  16, 0, 0);
        __builtin_amdgcn_global_load_lds(AS1(pA3), AS3(ab + 24576),  16, 0, 0);
        __builtin_amdgcn_global_load_lds(AS1(pA4), AS3(ab + 32768),  16, 0, 0);
        pA0 += 32; pA1 += 32; pA2 += 32; pA3 += 32; pA4 += 32;
    };

    const int rfr = lane & 15;
    const int cpr = lane >> 4;
    const int wm = wave >> 1;
    const int wn = wave & 1;
    const int arow = wm * 160 + rfr;
    const int ppA = (cpr + (arow >> 1)) & 3;
    const int aoff = arow * 32 + ppA * 8;

    // per-lane B register-load pointer (fragment-ordered; advances 32 elems/tile)
    const bf16_t* pB = Bt + ((size_t)(e * 2 + 0) * DIM + (ntile & 3) * 128 + wn * 64 + rfr) * K1
                       + cpr * 8;

    f32x4 acc[10][4] = {};

    // prologue: stage tile 0
    stage(0);

    for (int tt = 0; tt < 32; ++tt) {
        VMW(0);                                  // A-stage of tile tt fully landed
        __builtin_amdgcn_s_barrier();            // cross-wave visibility; buf (tt^1) free
        asm volatile("" ::: "memory");
        const bool st = (tt < 31);

        // B fragments for tile tt: oldest vmem of this tile (compiler waits vmcnt(5))
        bf16x8 bq[4];
        #pragma unroll
        for (int j = 0; j < 4; j++) bq[j] = *(const bf16x8*)(pB + (size_t)j * 16 * K1);
        pB += 32;

        if (st) stage((tt + 1) & 1);             // A-stage of tile tt+1 into free buffer

        const bf16_t* Ab = As + (tt & 1) * 20480 + aoff;
        bf16x8 aq[4];

        // ---- phase 0: A0-3, 16 MFMA ----
        #pragma unroll
        for (int i = 0; i < 4; i++) aq[i] = *(const bf16x8*)(Ab + i * 512);
        __builtin_amdgcn_s_barrier();
        asm volatile("s_waitcnt lgkmcnt(0)" ::: "memory");
        __builtin_amdgcn_sched_barrier(0);
        __builtin_amdgcn_s_setprio(1);
        #pragma unroll
        for (int i = 0; i < 4; i++)
            #pragma unroll
            for (int j = 0; j < 4; j++)
                MFMA16(acc[i][j], aq[i], bq[j]);
        __builtin_amdgcn_s_setprio(0);

        // ---- phase 1: A4-6, 12 MFMA ----
        #pragma unroll
        for (int i = 0; i < 3; i++) aq[i] = *(const bf16x8*)(Ab + (4 + i) * 512);
        __builtin_amdgcn_s_barrier();
        asm volatile("s_waitcnt lgkmcnt(0)" ::: "memory");
        __builtin_amdgcn_sched_barrier(0);
        __builtin_amdgcn_s_setprio(1);
        #pragma unroll
        for (int i = 0; i < 3; i++)
            #pragma unroll
            for (int j = 0; j < 4; j++)
                MFMA16(acc[4 + i][j], aq[i], bq[j]);
        __builtin_amdgcn_s_setprio(0);

        // ---- phase 2: A7-9, 12 MFMA ----
        #pragma unroll
        for (int i = 0; i < 3; i++) aq[i] = *(const bf16x8*)(Ab + (7 + i) * 512);
        __builtin_amdgcn_s_barrier();
        asm volatile("s_waitcnt lgkmcnt(0)" ::: "memory");
        __builtin_amdgcn_sched_barrier(0);
        __builtin_amdgcn_s_setprio(1);
        #pragma unroll
        for (int i = 0; i < 3; i++)
            #pragma unroll
            for (int j = 0; j < 4; j++)
                MFMA16(acc[7 + i][j], aq[i], bq[j]);
        __builtin_amdgcn_s_setprio(0);
        // no trailing barrier: next tile's VMW(0)+barrier is the cross-wave fence
    }

    // epilogue; C/D layout: col=lane&15, row=(lane>>4)*4+reg
    const float* bias = bias_all + e * 1024;
    const int cobase = (ntile & 3) * 128 + wn * 64 + (lane & 15);
    float bv[4];
    #pragma unroll
    for (int j = 0; j < 4; j++) bv[j] = bias[cobase + j * 16];
    const int rbase = mtile * 640 + wm * 160 + (lane >> 4) * 4;
    #pragma unroll
    for (int i = 0; i < 10; i++) {
        #pragma unroll
        for (int r = 0; r < 4; r++) {
            int row = rbase + i * 16 + r;
            if (row < N_NODES) {
                bf16_t* cp = h1 + ((size_t)e * N_NODES + row) * DIM + cobase;
                #pragma unroll
                for (int j = 0; j < 4; j++) {
                    float v = fmaxf(acc[i][j][r] + bv[j], 0.f);
                    cp[j * 16] = (bf16_t)v;
                }
            }
        }
    }
}

// ---------------- layer-2 GEMM: compact jobs + pipelined K-loop (r7-proven) ---------
__global__ __launch_bounds__(256)
void gemm2_kernel(const bf16_t* __restrict__ A,
                  const bf16_t* __restrict__ Bt,
                  const float* __restrict__ bias_all,
                  float* __restrict__ out,
                  const int* __restrict__ lists,
                  const int* __restrict__ ecnt,
                  const int* __restrict__ jobs,
                  const float* __restrict__ top_val) {
    __shared__ __align__(16) bf16_t As[3 * 128 * 32];
    __shared__ __align__(16) bf16_t Bs[3 * 128 * 32];

    const int t = threadIdx.x;
    const int lane = t & 63;
    const int wave = t >> 6;
    const int wm = wave >> 1;
    const int wn = wave & 1;
    const int r0 = t >> 2;
    const int rot = (t >> 3) & 3;
    const int cgl = ((t & 3) - rot) & 3;
    const int cpr = lane >> 4;
    const int rfr = lane & 15;
    char* asb = (char*)&As[0];
    char* bsb = (char*)&Bs[0];
    const int wb = wave * 1024;

    const int total = jobs[4] * 4;

    for (int j = blockIdx.x; j < total; j += gridDim.x) {
        const int byt = j >> 2;
        const int bx = j & 3;
        const int e = (byt >= jobs[1]) + (byt >= jobs[2]) + (byt >= jobs[3]);
        const int by = byt - jobs[e];
        const int cnt = ecnt[e];
        const int cmax = max(cnt, 1);

        int i0 = by * 128 + r0;
        int i1 = i0 + 64;
        int arow0 = lists[e * N_NODES + min(i0, cmax - 1)];
        int arow1 = lists[e * N_NODES + min(i1, cmax - 1)];
        arow0 = min(max(arow0, 0), N_NODES - 1);
        arow1 = min(max(arow1, 0), N_NODES - 1);
        const bf16_t* Bte = Bt + (size_t)(e * 2 + 1) * DIM * K1;
        const bf16_t* aptr0 = A + (size_t)arow0 * K1 + cgl * 8;
        const bf16_t* aptr1 = A + (size_t)arow1 * K1 + cgl * 8;
        const bf16_t* bptr0 = Bte + (size_t)(bx * 128 + r0) * K1 + cgl * 8;
        const bf16_t* bptr1 = bptr0 + (size_t)64 * K1;

        f32x4 acc[4][4] = {};

        auto stage = [&](int bu) {
            char* ab = asb + bu * 8192 + wb;
            char* bb = bsb + bu * 8192 + wb;
            __builtin_amdgcn_global_load_lds(AS1(aptr0), AS3(ab),        16, 0, 0);
            __builtin_amdgcn_global_load_lds(AS1(aptr1), AS3(ab + 4096), 16, 0, 0);
            __builtin_amdgcn_global_load_lds(AS1(bptr0), AS3(bb),        16, 0, 0);
            __builtin_amdgcn_global_load_lds(AS1(bptr1), AS3(bb + 4096), 16, 0, 0);
            aptr0 += 32; aptr1 += 32; bptr0 += 32; bptr1 += 32;
        };

        auto compute = [&](int bu) {
            const bf16_t* Ab = As + bu * 4096;
            const bf16_t* Bb = Bs + bu * 4096;
            bf16x8 af[4], bfr[4];
            #pragma unroll
            for (int i = 0; i < 4; i++) {
                int r_full = wm * 64 + i * 16 + rfr;
                int p = (cpr + (r_full >> 1)) & 3;
                af[i] = *(const bf16x8*)(Ab + r_full * 32 + p * 8);
            }
            #pragma unroll
            for (int jj = 0; jj < 4; jj++) {
                int r_full = wn * 64 + jj * 16 + rfr;
                int p = (cpr + (r_full >> 1)) & 3;
                bfr[jj] = *(const bf16x8*)(Bb + r_full * 32 + p * 8);
            }
            #pragma unroll
            for (int i = 0; i < 4; i++)
                #pragma unroll
                for (int jj = 0; jj < 4; jj++)
                    MFMA16(acc[i][jj], af[i], bfr[jj]);
        };

        __builtin_amdgcn_s_barrier();
        asm volatile("" ::: "memory");

        stage(0);
        stage(1);
        int cb = 0, sb = 2;
        for (int tt = 0; tt < 31; ++tt) {
            VMW(4);
            __builtin_amdgcn_s_barrier();
            asm volatile("" ::: "memory");
            if (tt < 30) {
                stage(sb);
                sb = (sb == 2) ? 0 : sb + 1;
            }
            compute(cb);
            cb = (cb == 2) ? 0 : cb + 1;
        }
        VMW(0);
        __builtin_amdgcn_s_barrier();
        asm volatile("" ::: "memory");
        compute(cb);

        const float* bias = bias_all + e * 1024 + DIM;
        const int cbase = bx * 128 + wn * 64 + (lane & 15);
        float bv[4];
        #pragma unroll
        for (int jj = 0; jj < 4; jj++) bv[jj] = bias[cbase + jj * 16];
        #pragma unroll
        for (int i = 0; i < 4; i++) {
            #pragma unroll
            for (int r = 0; r < 4; r++) {
                int row = by * 128 + wm * 64 + i * 16 + (lane >> 4) * 4 + r;
                if (row < cnt) {
                    int node = lists[e * N_NODES + row];
                    float tv = top_val[node];
                    float* cp = out + (size_t)node * DIM + cbase;
                    #pragma unroll
                    for (int jj = 0; jj < 4; jj++) {
                        float v = fmaxf(acc[i][jj][r] + bv[jj], 0.f);
                        cp[jj * 16] = v * tv;
                    }
                }
            }
        }
    }
}

extern "C" void kernel_launch(void* const* d_in, const int* in_sizes, int n_in,
                              void* d_out, int out_size, void* d_ws, size_t ws_size,
                              hipStream_t stream) {
    const float* x       = (const float*)d_in[0];
    const int*   edge    = (const int*)d_in[1];
    const float* gw      = (const float*)d_in[2];
    const float* gb      = (const float*)d_in[3];
    const float* w_self  = (const float*)d_in[4];
    const float* w_neigh = (const float*)d_in[5];
    const float* b_exp   = (const float*)d_in[6];
    float* out = (float*)d_out;

    char* p = (char*)d_ws;
    auto alloc = [&](size_t bytes) {
        char* r = p;
        p += (bytes + 255) & ~(size_t)255;
        return r;
    };
    bf16_t* Bt      = (bf16_t*)alloc((size_t)8 * DIM * K1 * 2);
    bf16_t* acat    = (bf16_t*)alloc((size_t)N_NODES * K1 * 2);
    bf16_t* h1      = (bf16_t*)alloc((size_t)NEXP * N_NODES * DIM * 2);
    int*    deg     = (int*)alloc((size_t)N_NODES * 4);
    int*    offs    = (int*)alloc((size_t)(N_NODES + 1) * 4);
    int*    cursor  = (int*)alloc((size_t)N_NODES * 4);
    int*    csr     = (int*)alloc((size_t)N_EDGES * 4);
    int*    top_idx = (int*)alloc((size_t)N_NODES * 4);
    float*  top_val = (float*)alloc((size_t)N_NODES * 4);
    int*    ecnt    = (int*)alloc(256);
    int*    lists   = (int*)alloc((size_t)NEXP * N_NODES * 4);
    int*    jobs    = ecnt + 8;

    const int* srcE = edge;
    const int* dstE = edge + N_EDGES;

    gate_kernel<<<N_NODES / 4, 256, 0, stream>>>(x, gw, gb, top_idx, top_val, acat, deg, ecnt);
    bucket_deg_kernel<<<N_EDGES / 256, 256, 0, stream>>>(top_idx, ecnt, lists, dstE, deg);
    scan_kernel<<<1, 1024, 0, stream>>>(deg, offs, cursor, ecnt, jobs);
    fill_wtrans_kernel<<<625 + 4096, 256, 0, stream>>>(srcE, dstE, cursor, csr, w_neigh, w_self, Bt);
    agg1_kernel<<<N_NODES / 4, 256, 0, stream>>>(offs, csr, acat);
    gemm_l1_kernel<<<256, 512, 0, stream>>>(acat, Bt, b_exp, h1);
    agg2_kernel<<<N_NODES / 4, 256, 0, stream>>>(offs, csr, top_idx, h1, acat);
    gemm2_kernel<<<320, 256, 0, stream>>>(acat, Bt, b_exp, out, lists, ecnt, jobs, top_val);
}

// Round 13
// 263.930 us; speedup vs baseline: 1.1217x; 1.1217x over previous
//
#include <hip/hip_runtime.h>
#include <hip/hip_bf16.h>
#include <cstdint>

#define N_NODES 10000
#define N_EDGES 160000
#define DIM 512
#define K1 1024
#define NEXP 4

typedef __bf16 bf16_t;
typedef bf16_t bf16x8 __attribute__((ext_vector_type(8)));
typedef float f32x4 __attribute__((ext_vector_type(4)));

#define AS1(p) ((__attribute__((address_space(1))) void*)(p))
#define AS3(p) ((__attribute__((address_space(3))) void*)(p))

#define VMW(N) asm volatile("s_waitcnt vmcnt(" #N ")" ::: "memory")
#define MFMA16(d, a_, b_) d = __builtin_amdgcn_mfma_f32_16x16x32_bf16(a_, b_, d, 0, 0, 0)

// ---------------- gating + x->bf16 + counter zeroing (fused; r9-proven) ---------
__global__ void gate_kernel(const float* __restrict__ x,
                            const float* __restrict__ gw,
                            const float* __restrict__ gb,
                            int* __restrict__ top_idx,
                            float* __restrict__ top_val,
                            bf16_t* __restrict__ acat,
                            int* __restrict__ deg,
                            int* __restrict__ ecnt) {
    const int gid = blockIdx.x * 256 + threadIdx.x;
    if (gid < N_NODES) deg[gid] = 0;
    if (gid < NEXP) ecnt[gid] = 0;

    const int wave = threadIdx.x >> 6;
    const int lane = threadIdx.x & 63;
    const int node = blockIdx.x * 4 + wave;
    if (node >= N_NODES) return;
    const float4* x4 = (const float4*)(x + (size_t)node * DIM);
    const float4* gw4 = (const float4*)gw;
    float4 xa = x4[lane * 2];
    float4 xb = x4[lane * 2 + 1];
    float xv[8] = { xa.x, xa.y, xa.z, xa.w, xb.x, xb.y, xb.z, xb.w };
    float a0 = 0.f, a1 = 0.f, a2 = 0.f, a3 = 0.f;
    #pragma unroll
    for (int c = 0; c < 8; c++) {
        float4 g = gw4[lane * 8 + c];
        a0 += xv[c] * g.x; a1 += xv[c] * g.y; a2 += xv[c] * g.z; a3 += xv[c] * g.w;
    }
    bf16x8 o;
    #pragma unroll
    for (int c = 0; c < 8; c++) o[c] = (bf16_t)xv[c];
    *(bf16x8*)(acat + (size_t)node * K1 + DIM + lane * 8) = o;
    for (int off = 32; off > 0; off >>= 1) {
        a0 += __shfl_xor(a0, off);
        a1 += __shfl_xor(a1, off);
        a2 += __shfl_xor(a2, off);
        a3 += __shfl_xor(a3, off);
    }
    if (lane == 0) {
        float z[4] = { a0 + gb[0], a1 + gb[1], a2 + gb[2], a3 + gb[3] };
        int bi = 0; float bm = z[0];
        for (int e = 1; e < 4; e++) if (z[e] > bm) { bm = z[e]; bi = e; }
        float den = 0.f;
        for (int e = 0; e < 4; e++) den += expf(z[e] - bm);
        top_idx[node] = bi;
        top_val[node] = 1.0f / den;
    }
}

// ---------------- expert bucketing + degree count (fused; r9-proven) ---
__global__ void bucket_deg_kernel(const int* __restrict__ top_idx,
                                  int* __restrict__ ecnt,
                                  int* __restrict__ lists,
                                  const int* __restrict__ dst,
                                  int* __restrict__ deg) {
    const int gi = blockIdx.x * 256 + threadIdx.x;
    if (gi < N_EDGES) atomicAdd(&deg[dst[gi]], 1);

    if (blockIdx.x < 40) {
        __shared__ int lcnt[NEXP];
        __shared__ int base[NEXP];
        const int tid = threadIdx.x;
        if (tid < NEXP) lcnt[tid] = 0;
        __syncthreads();
        const int node = blockIdx.x * 256 + tid;
        int e = 0, rank = 0;
        if (node < N_NODES) {
            e = top_idx[node];
            rank = atomicAdd(&lcnt[e], 1);
        }
        __syncthreads();
        if (tid < NEXP) base[tid] = atomicAdd(&ecnt[tid], lcnt[tid]);
        __syncthreads();
        if (node < N_NODES) lists[e * N_NODES + base[e] + rank] = node;
    }
}

// scan + layer-2 job table (fused; r9-proven)
__global__ void scan_kernel(const int* __restrict__ deg,
                            int* __restrict__ offs,
                            int* __restrict__ cursor,
                            const int* __restrict__ ecnt,
                            int* __restrict__ jobs) {
    __shared__ int wsum[16];
    __shared__ int carrysh;
    const int tid = threadIdx.x;
    const int lane = tid & 63;
    const int wv = tid >> 6;
    if (tid == 0) {
        carrysh = 0;
        int pref = 0;
        for (int e2 = 0; e2 < NEXP; e2++) {
            jobs[e2] = pref;
            pref += (ecnt[e2] + 127) >> 7;
        }
        jobs[4] = pref;
    }
    __syncthreads();
    for (int base = 0; base < N_NODES; base += 1024) {
        int i = base + tid;
        int v = (i < N_NODES) ? deg[i] : 0;
        int s = v;
        #pragma unroll
        for (int off = 1; off < 64; off <<= 1) {
            int t = __shfl_up(s, off);
            if (lane >= off) s += t;
        }
        if (lane == 63) wsum[wv] = s;
        int carry = carrysh;
        __syncthreads();
        if (wv == 0) {
            int w = (lane < 16) ? wsum[lane] : 0;
            #pragma unroll
            for (int off = 1; off < 16; off <<= 1) {
                int t = __shfl_up(w, off);
                if (lane >= off) w += t;
            }
            if (lane < 16) wsum[lane] = w;
        }
        __syncthreads();
        int wbase = (wv > 0) ? wsum[wv - 1] : 0;
        int excl = carry + wbase + s - v;
        if (i < N_NODES) { offs[i] = excl; cursor[i] = excl; }
        int total = wsum[15];
        __syncthreads();
        if (tid == 0) carrysh = carry + total;
        __syncthreads();
    }
    if (tid == 0) offs[N_NODES] = carrysh;
}

// ---------------- CSR fill + weight transpose (fused; r9-proven) ------------
__global__ void fill_wtrans_kernel(const int* __restrict__ src, const int* __restrict__ dst,
                                   int* __restrict__ cursor, int* __restrict__ csr,
                                   const float* __restrict__ w_neigh,
                                   const float* __restrict__ w_self,
                                   bf16_t* __restrict__ Bt) {
    if (blockIdx.x < 625) {
        int i = blockIdx.x * 256 + threadIdx.x;
        if (i < N_EDGES) {
            int d = dst[i];
            int p = atomicAdd(&cursor[d], 1);
            csr[p] = src[i];
        }
    } else {
        __shared__ float tile[32][33];
        const int q = blockIdx.x - 625;
        const int m = q >> 8;
        const bool isSelf = m >= 8;
        const int el = m & 7;
        const float* W = (isSelf ? w_self : w_neigh) + (size_t)el * DIM * DIM;
        const int k0 = (q & 15) * 32;
        const int n0 = ((q >> 4) & 15) * 32;
        const int tx = threadIdx.x & 31, ty = threadIdx.x >> 5;
        for (int r = ty; r < 32; r += 8)
            tile[r][tx] = W[(size_t)(k0 + r) * DIM + n0 + tx];
        __syncthreads();
        for (int r = ty; r < 32; r += 8) {
            int n = n0 + r;
            int k = k0 + tx;
            Bt[((size_t)el * DIM + n) * K1 + (isSelf ? DIM : 0) + k] = (bf16_t)tile[tx][r];
        }
    }
}

// ---------------- agg1: mean of x rows into acat cols 0..511, unroll 8 ----------------
__global__ void agg1_kernel(const int* __restrict__ offs, const int* __restrict__ csr,
                            bf16_t* __restrict__ acat) {
    const int wave = threadIdx.x >> 6;
    const int lane = threadIdx.x & 63;
    const int node = blockIdx.x * 4 + wave;
    if (node >= N_NODES) return;
    const int c0 = lane * 8;
    float s[8] = {0,0,0,0,0,0,0,0};
    int beg = offs[node];
    int end = offs[node + 1];
    int d = end - beg;
    int p = beg;
    for (; p + 8 <= end; p += 8) {
        bf16x8 v[8];
        #pragma unroll
        for (int q = 0; q < 8; q++) {
            int idx = csr[p + q];
            v[q] = *(const bf16x8*)(acat + (size_t)idx * K1 + DIM + c0);
        }
        #pragma unroll
        for (int q = 0; q < 8; q++)
            #pragma unroll
            for (int k = 0; k < 8; k++) s[k] += (float)v[q][k];
    }
    for (; p + 4 <= end; p += 4) {
        bf16x8 v[4];
        #pragma unroll
        for (int q = 0; q < 4; q++) {
            int idx = csr[p + q];
            v[q] = *(const bf16x8*)(acat + (size_t)idx * K1 + DIM + c0);
        }
        #pragma unroll
        for (int q = 0; q < 4; q++)
            #pragma unroll
            for (int k = 0; k < 8; k++) s[k] += (float)v[q][k];
    }
    for (; p < end; p++) {
        int idx = csr[p];
        bf16x8 v0 = *(const bf16x8*)(acat + (size_t)idx * K1 + DIM + c0);
        #pragma unroll
        for (int k = 0; k < 8; k++) s[k] += (float)v0[k];
    }
    float w = d > 0 ? 1.0f / (float)d : 0.0f;
    bf16x8 o;
    #pragma unroll
    for (int k = 0; k < 8; k++) o[k] = (bf16_t)(s[k] * w);
    *(bf16x8*)(acat + (size_t)node * K1 + c0) = o;
}

// ---------------- agg2: selected-expert mean of h1 rows + self copy, unroll 8 ----------------
__global__ void agg2_kernel(const int* __restrict__ offs, const int* __restrict__ csr,
                            const int* __restrict__ top_idx,
                            const bf16_t* __restrict__ h1, bf16_t* __restrict__ acat) {
    const int wave = threadIdx.x >> 6;
    const int lane = threadIdx.x & 63;
    const int node = blockIdx.x * 4 + wave;
    if (node >= N_NODES) return;
    const int c0 = lane * 8;
    const bf16_t* hb = h1 + (size_t)top_idx[node] * N_NODES * DIM;
    float s[8] = {0,0,0,0,0,0,0,0};
    int beg = offs[node];
    int end = offs[node + 1];
    int d = end - beg;
    int p = beg;
    for (; p + 8 <= end; p += 8) {
        bf16x8 v[8];
        #pragma unroll
        for (int q = 0; q < 8; q++) {
            int idx = csr[p + q];
            v[q] = *(const bf16x8*)(hb + (size_t)idx * DIM + c0);
        }
        #pragma unroll
        for (int q = 0; q < 8; q++)
            #pragma unroll
            for (int k = 0; k < 8; k++) s[k] += (float)v[q][k];
    }
    for (; p + 4 <= end; p += 4) {
        bf16x8 v[4];
        #pragma unroll
        for (int q = 0; q < 4; q++) {
            int idx = csr[p + q];
            v[q] = *(const bf16x8*)(hb + (size_t)idx * DIM + c0);
        }
        #pragma unroll
        for (int q = 0; q < 4; q++)
            #pragma unroll
            for (int k = 0; k < 8; k++) s[k] += (float)v[q][k];
    }
    for (; p < end; p++) {
        int idx = csr[p];
        bf16x8 v0 = *(const bf16x8*)(hb + (size_t)idx * DIM + c0);
        #pragma unroll
        for (int k = 0; k < 8; k++) s[k] += (float)v0[k];
    }
    float w = d > 0 ? 1.0f / (float)d : 0.0f;
    bf16x8 o;
    #pragma unroll
    for (int k = 0; k < 8; k++) o[k] = (bf16_t)(s[k] * w);
    *(bf16x8*)(acat + (size_t)node * K1 + c0) = o;
    *(bf16x8*)(acat + (size_t)node * K1 + DIM + c0) = *(const bf16x8*)(hb + (size_t)node * DIM + c0);
}

// ---------------- layer-1 GEMM: 640x128, 3-phase schedule, 4 barriers/tile (r8) -----
// FINAL: best measured variant (50.8 us, MfmaUtil 32.4%). Variants r3/r4/r9/r12
// (53/57.5/53.4/81) all confirmed this as the fixed point. r12's B-from-global
// refuted the LDS-port-redundancy model (uncoalesced 16-row strided B loads: 81 us).
__global__ __launch_bounds__(512, 2)
void gemm_l1_kernel(const bf16_t* __restrict__ A,
                    const bf16_t* __restrict__ Bt,
                    const float* __restrict__ bias_all,
                    bf16_t* __restrict__ h1) {
    const int b = blockIdx.x;
    const int xcd = b & 7;
    const int loc = b >> 3;
    const int mtile = xcd * 2 + (loc >> 4);
    const int ntile = loc & 15;
    const int e = ntile >> 2;

    __shared__ __align__(16) bf16_t As[3 * 640 * 32];
    __shared__ __align__(16) bf16_t Bs[3 * 128 * 32];

    const int t = threadIdx.x;
    const int lane = t & 63;
    const int wave = t >> 6;
    const int rloc = t >> 2;
    const int cgl = ((t & 3) - ((t >> 3) & 3)) & 3;

    const bf16_t* pA0 = A + (size_t)min(mtile * 640 +   0 + rloc, N_NODES - 1) * K1 + cgl * 8;
    const bf16_t* pA1 = A + (size_t)min(mtile * 640 + 128 + rloc, N_NODES - 1) * K1 + cgl * 8;
    const bf16_t* pA2 = A + (size_t)min(mtile * 640 + 256 + rloc, N_NODES - 1) * K1 + cgl * 8;
    const bf16_t* pA3 = A + (size_t)min(mtile * 640 + 384 + rloc, N_NODES - 1) * K1 + cgl * 8;
    const bf16_t* pA4 = A + (size_t)min(mtile * 640 + 512 + rloc, N_NODES - 1) * K1 + cgl * 8;
    const bf16_t* pB0 = Bt + ((size_t)(e * 2 + 0) * DIM + (ntile & 3) * 128 + rloc) * K1 + cgl * 8;

    char* asb = (char*)&As[0];
    char* bsb = (char*)&Bs[0];

    auto stage_full = [&](int bu) {
        char* ab = asb + bu * 40960 + wave * 1024;
        char* bb = bsb + bu * 8192  + wave * 1024;
        __builtin_amdgcn_global_load_lds(AS1(pA0), AS3(ab),          16, 0, 0);
        __builtin_amdgcn_global_load_lds(AS1(pA1), AS3(ab + 8192),   16, 0, 0);
        __builtin_amdgcn_global_load_lds(AS1(pA2), AS3(ab + 16384),  16, 0, 0);
        __builtin_amdgcn_global_load_lds(AS1(pA3), AS3(ab + 24576),  16, 0, 0);
        __builtin_amdgcn_global_load_lds(AS1(pA4), AS3(ab + 32768),  16, 0, 0);
        __builtin_amdgcn_global_load_lds(AS1(pB0), AS3(bb),          16, 0, 0);
        pA0 += 32; pA1 += 32; pA2 += 32; pA3 += 32; pA4 += 32; pB0 += 32;
    };

    const int rfr = lane & 15;
    const int cpr = lane >> 4;
    const int wm = wave >> 1;
    const int wn = wave & 1;
    const int arow = wm * 160 + rfr;
    const int brow = wn * 64 + rfr;
    const int ppA = (cpr + (arow >> 1)) & 3;
    const int ppB = (cpr + (brow >> 1)) & 3;
    const int aoff = arow * 32 + ppA * 8;
    const int boff = brow * 32 + ppB * 8;

    f32x4 acc[10][4] = {};

    auto compute_full = [&](int bu) {
        const bf16_t* Ab = As + bu * 20480 + aoff;
        const bf16_t* Bb = Bs + bu * 4096  + boff;
        bf16x8 bfr[4];
        #pragma unroll
        for (int j = 0; j < 4; j++) bfr[j] = *(const bf16x8*)(Bb + j * 512);
        #pragma unroll
        for (int i = 0; i < 10; i++) {
            bf16x8 af = *(const bf16x8*)(Ab + i * 512);
            #pragma unroll
            for (int j = 0; j < 4; j++)
                MFMA16(acc[i][j], af, bfr[j]);
        }
    };

    stage_full(0);
    stage_full(1);

    int cb = 0, sb = 2;
    for (int tt = 0; tt < 31; ++tt) {
        VMW(6);
        __builtin_amdgcn_s_barrier();
        asm volatile("" ::: "memory");
        const bool st = (tt < 30);
        char* ab = asb + sb * 40960 + wave * 1024;
        char* bb = bsb + sb * 8192  + wave * 1024;
        const bf16_t* Ab = As + cb * 20480 + aoff;
        const bf16_t* Bb = Bs + cb * 4096  + boff;

        bf16x8 bq[4], aq[4];

        #pragma unroll
        for (int j = 0; j < 4; j++) bq[j] = *(const bf16x8*)(Bb + j * 512);
        #pragma unroll
        for (int i = 0; i < 4; i++) aq[i] = *(const bf16x8*)(Ab + i * 512);
        if (st) {
            __builtin_amdgcn_global_load_lds(AS1(pA0), AS3(ab),        16, 0, 0);
            __builtin_amdgcn_global_load_lds(AS1(pA1), AS3(ab + 8192), 16, 0, 0);
        }
        __builtin_amdgcn_s_barrier();
        asm volatile("s_waitcnt lgkmcnt(0)" ::: "memory");
        __builtin_amdgcn_sched_barrier(0);
        __builtin_amdgcn_s_setprio(1);
        #pragma unroll
        for (int i = 0; i < 4; i++)
            #pragma unroll
            for (int j = 0; j < 4; j++)
                MFMA16(acc[i][j], aq[i], bq[j]);
        __builtin_amdgcn_s_setprio(0);

        #pragma unroll
        for (int i = 0; i < 3; i++) aq[i] = *(const bf16x8*)(Ab + (4 + i) * 512);
        if (st) {
            __builtin_amdgcn_global_load_lds(AS1(pA2), AS3(ab + 16384), 16, 0, 0);
            __builtin_amdgcn_global_load_lds(AS1(pA3), AS3(ab + 24576), 16, 0, 0);
        }
        __builtin_amdgcn_s_barrier();
        asm volatile("s_waitcnt lgkmcnt(0)" ::: "memory");
        __builtin_amdgcn_sched_barrier(0);
        __builtin_amdgcn_s_setprio(1);
        #pragma unroll
        for (int i = 0; i < 3; i++)
            #pragma unroll
            for (int j = 0; j < 4; j++)
                MFMA16(acc[4 + i][j], aq[i], bq[j]);
        __builtin_amdgcn_s_setprio(0);

        #pragma unroll
        for (int i = 0; i < 3; i++) aq[i] = *(const bf16x8*)(Ab + (7 + i) * 512);
        if (st) {
            __builtin_amdgcn_global_load_lds(AS1(pA4), AS3(ab + 32768), 16, 0, 0);
            __builtin_amdgcn_global_load_lds(AS1(pB0), AS3(bb),         16, 0, 0);
        }
        __builtin_amdgcn_s_barrier();
        asm volatile("s_waitcnt lgkmcnt(0)" ::: "memory");
        __builtin_amdgcn_sched_barrier(0);
        __builtin_amdgcn_s_setprio(1);
        #pragma unroll
        for (int i = 0; i < 3; i++)
            #pragma unroll
            for (int j = 0; j < 4; j++)
                MFMA16(acc[7 + i][j], aq[i], bq[j]);
        __builtin_amdgcn_s_setprio(0);

        if (st) {
            pA0 += 32; pA1 += 32; pA2 += 32; pA3 += 32; pA4 += 32; pB0 += 32;
            sb = (sb == 2) ? 0 : sb + 1;
        }
        cb = (cb == 2) ? 0 : cb + 1;
    }
    VMW(0);
    __builtin_amdgcn_s_barrier();
    asm volatile("" ::: "memory");
    compute_full(cb);

    const float* bias = bias_all + e * 1024;
    const int cobase = (ntile & 3) * 128 + wn * 64 + (lane & 15);
    float bv[4];
    #pragma unroll
    for (int j = 0; j < 4; j++) bv[j] = bias[cobase + j * 16];
    const int rbase = mtile * 640 + wm * 160 + (lane >> 4) * 4;
    #pragma unroll
    for (int i = 0; i < 10; i++) {
        #pragma unroll
        for (int r = 0; r < 4; r++) {
            int row = rbase + i * 16 + r;
            if (row < N_NODES) {
                bf16_t* cp = h1 + ((size_t)e * N_NODES + row) * DIM + cobase;
                #pragma unroll
                for (int j = 0; j < 4; j++) {
                    float v = fmaxf(acc[i][j][r] + bv[j], 0.f);
                    cp[j * 16] = (bf16_t)v;
                }
            }
        }
    }
}

// ---------------- layer-2 GEMM: compact jobs + pipelined K-loop (r7-proven) ---------
__global__ __launch_bounds__(256)
void gemm2_kernel(const bf16_t* __restrict__ A,
                  const bf16_t* __restrict__ Bt,
                  const float* __restrict__ bias_all,
                  float* __restrict__ out,
                  const int* __restrict__ lists,
                  const int* __restrict__ ecnt,
                  const int* __restrict__ jobs,
                  const float* __restrict__ top_val) {
    __shared__ __align__(16) bf16_t As[3 * 128 * 32];
    __shared__ __align__(16) bf16_t Bs[3 * 128 * 32];

    const int t = threadIdx.x;
    const int lane = t & 63;
    const int wave = t >> 6;
    const int wm = wave >> 1;
    const int wn = wave & 1;
    const int r0 = t >> 2;
    const int rot = (t >> 3) & 3;
    const int cgl = ((t & 3) - rot) & 3;
    const int cpr = lane >> 4;
    const int rfr = lane & 15;
    char* asb = (char*)&As[0];
    char* bsb = (char*)&Bs[0];
    const int wb = wave * 1024;

    const int total = jobs[4] * 4;

    for (int j = blockIdx.x; j < total; j += gridDim.x) {
        const int byt = j >> 2;
        const int bx = j & 3;
        const int e = (byt >= jobs[1]) + (byt >= jobs[2]) + (byt >= jobs[3]);
        const int by = byt - jobs[e];
        const int cnt = ecnt[e];
        const int cmax = max(cnt, 1);

        int i0 = by * 128 + r0;
        int i1 = i0 + 64;
        int arow0 = lists[e * N_NODES + min(i0, cmax - 1)];
        int arow1 = lists[e * N_NODES + min(i1, cmax - 1)];
        arow0 = min(max(arow0, 0), N_NODES - 1);
        arow1 = min(max(arow1, 0), N_NODES - 1);
        const bf16_t* Bte = Bt + (size_t)(e * 2 + 1) * DIM * K1;
        const bf16_t* aptr0 = A + (size_t)arow0 * K1 + cgl * 8;
        const bf16_t* aptr1 = A + (size_t)arow1 * K1 + cgl * 8;
        const bf16_t* bptr0 = Bte + (size_t)(bx * 128 + r0) * K1 + cgl * 8;
        const bf16_t* bptr1 = bptr0 + (size_t)64 * K1;

        f32x4 acc[4][4] = {};

        auto stage = [&](int bu) {
            char* ab = asb + bu * 8192 + wb;
            char* bb = bsb + bu * 8192 + wb;
            __builtin_amdgcn_global_load_lds(AS1(aptr0), AS3(ab),        16, 0, 0);
            __builtin_amdgcn_global_load_lds(AS1(aptr1), AS3(ab + 4096), 16, 0, 0);
            __builtin_amdgcn_global_load_lds(AS1(bptr0), AS3(bb),        16, 0, 0);
            __builtin_amdgcn_global_load_lds(AS1(bptr1), AS3(bb + 4096), 16, 0, 0);
            aptr0 += 32; aptr1 += 32; bptr0 += 32; bptr1 += 32;
        };

        auto compute = [&](int bu) {
            const bf16_t* Ab = As + bu * 4096;
            const bf16_t* Bb = Bs + bu * 4096;
            bf16x8 af[4], bfr[4];
            #pragma unroll
            for (int i = 0; i < 4; i++) {
                int r_full = wm * 64 + i * 16 + rfr;
                int p = (cpr + (r_full >> 1)) & 3;
                af[i] = *(const bf16x8*)(Ab + r_full * 32 + p * 8);
            }
            #pragma unroll
            for (int jj = 0; jj < 4; jj++) {
                int r_full = wn * 64 + jj * 16 + rfr;
                int p = (cpr + (r_full >> 1)) & 3;
                bfr[jj] = *(const bf16x8*)(Bb + r_full * 32 + p * 8);
            }
            #pragma unroll
            for (int i = 0; i < 4; i++)
                #pragma unroll
                for (int jj = 0; jj < 4; jj++)
                    MFMA16(acc[i][jj], af[i], bfr[jj]);
        };

        __builtin_amdgcn_s_barrier();
        asm volatile("" ::: "memory");

        stage(0);
        stage(1);
        int cb = 0, sb = 2;
        for (int tt = 0; tt < 31; ++tt) {
            VMW(4);
            __builtin_amdgcn_s_barrier();
            asm volatile("" ::: "memory");
            if (tt < 30) {
                stage(sb);
                sb = (sb == 2) ? 0 : sb + 1;
            }
            compute(cb);
            cb = (cb == 2) ? 0 : cb + 1;
        }
        VMW(0);
        __builtin_amdgcn_s_barrier();
        asm volatile("" ::: "memory");
        compute(cb);

        const float* bias = bias_all + e * 1024 + DIM;
        const int cbase = bx * 128 + wn * 64 + (lane & 15);
        float bv[4];
        #pragma unroll
        for (int jj = 0; jj < 4; jj++) bv[jj] = bias[cbase + jj * 16];
        #pragma unroll
        for (int i = 0; i < 4; i++) {
            #pragma unroll
            for (int r = 0; r < 4; r++) {
                int row = by * 128 + wm * 64 + i * 16 + (lane >> 4) * 4 + r;
                if (row < cnt) {
                    int node = lists[e * N_NODES + row];
                    float tv = top_val[node];
                    float* cp = out + (size_t)node * DIM + cbase;
                    #pragma unroll
                    for (int jj = 0; jj < 4; jj++) {
                        float v = fmaxf(acc[i][jj][r] + bv[jj], 0.f);
                        cp[jj * 16] = v * tv;
                    }
                }
            }
        }
    }
}

extern "C" void kernel_launch(void* const* d_in, const int* in_sizes, int n_in,
                              void* d_out, int out_size, void* d_ws, size_t ws_size,
                              hipStream_t stream) {
    const float* x       = (const float*)d_in[0];
    const int*   edge    = (const int*)d_in[1];
    const float* gw      = (const float*)d_in[2];
    const float* gb      = (const float*)d_in[3];
    const float* w_self  = (const float*)d_in[4];
    const float* w_neigh = (const float*)d_in[5];
    const float* b_exp   = (const float*)d_in[6];
    float* out = (float*)d_out;

    char* p = (char*)d_ws;
    auto alloc = [&](size_t bytes) {
        char* r = p;
        p += (bytes + 255) & ~(size_t)255;
        return r;
    };
    bf16_t* Bt      = (bf16_t*)alloc((size_t)8 * DIM * K1 * 2);
    bf16_t* acat    = (bf16_t*)alloc((size_t)N_NODES * K1 * 2);
    bf16_t* h1      = (bf16_t*)alloc((size_t)NEXP * N_NODES * DIM * 2);
    int*    deg     = (int*)alloc((size_t)N_NODES * 4);
    int*    offs    = (int*)alloc((size_t)(N_NODES + 1) * 4);
    int*    cursor  = (int*)alloc((size_t)N_NODES * 4);
    int*    csr     = (int*)alloc((size_t)N_EDGES * 4);
    int*    top_idx = (int*)alloc((size_t)N_NODES * 4);
    float*  top_val = (float*)alloc((size_t)N_NODES * 4);
    int*    ecnt    = (int*)alloc(256);
    int*    lists   = (int*)alloc((size_t)NEXP * N_NODES * 4);
    int*    jobs    = ecnt + 8;

    const int* srcE = edge;
    const int* dstE = edge + N_EDGES;

    gate_kernel<<<N_NODES / 4, 256, 0, stream>>>(x, gw, gb, top_idx, top_val, acat, deg, ecnt);
    bucket_deg_kernel<<<N_EDGES / 256, 256, 0, stream>>>(top_idx, ecnt, lists, dstE, deg);
    scan_kernel<<<1, 1024, 0, stream>>>(deg, offs, cursor, ecnt, jobs);
    fill_wtrans_kernel<<<625 + 4096, 256, 0, stream>>>(srcE, dstE, cursor, csr, w_neigh, w_self, Bt);
    agg1_kernel<<<N_NODES / 4, 256, 0, stream>>>(offs, csr, acat);
    gemm_l1_kernel<<<256, 512, 0, stream>>>(acat, Bt, b_exp, h1);
    agg2_kernel<<<N_NODES / 4, 256, 0, stream>>>(offs, csr, top_idx, h1, acat);
    gemm2_kernel<<<320, 256, 0, stream>>>(acat, Bt, b_exp, out, lists, ecnt, jobs, top_val);
}

// Round 14
// 263.456 us; speedup vs baseline: 1.1237x; 1.0018x over previous
//
#include <hip/hip_runtime.h>
#include <hip/hip_bf16.h>
#include <cstdint>

#define N_NODES 10000
#define N_EDGES 160000
#define DIM 512
#define K1 1024
#define NEXP 4

typedef __bf16 bf16_t;
typedef bf16_t bf16x8 __attribute__((ext_vector_type(8)));
typedef float f32x4 __attribute__((ext_vector_type(4)));

#define AS1(p) ((__attribute__((address_space(1))) void*)(p))
#define AS3(p) ((__attribute__((address_space(3))) void*)(p))

#define VMW(N) asm volatile("s_waitcnt vmcnt(" #N ")" ::: "memory")
#define MFMA16(d, a_, b_) d = __builtin_amdgcn_mfma_f32_16x16x32_bf16(a_, b_, d, 0, 0, 0)

// ---------------- gating + x->bf16 + counter zeroing (fused; r9-proven) ---------
__global__ void gate_kernel(const float* __restrict__ x,
                            const float* __restrict__ gw,
                            const float* __restrict__ gb,
                            int* __restrict__ top_idx,
                            float* __restrict__ top_val,
                            bf16_t* __restrict__ acat,
                            int* __restrict__ deg,
                            int* __restrict__ ecnt) {
    const int gid = blockIdx.x * 256 + threadIdx.x;
    if (gid < N_NODES) deg[gid] = 0;
    if (gid < NEXP) ecnt[gid] = 0;

    const int wave = threadIdx.x >> 6;
    const int lane = threadIdx.x & 63;
    const int node = blockIdx.x * 4 + wave;
    if (node >= N_NODES) return;
    const float4* x4 = (const float4*)(x + (size_t)node * DIM);
    const float4* gw4 = (const float4*)gw;
    float4 xa = x4[lane * 2];
    float4 xb = x4[lane * 2 + 1];
    float xv[8] = { xa.x, xa.y, xa.z, xa.w, xb.x, xb.y, xb.z, xb.w };
    float a0 = 0.f, a1 = 0.f, a2 = 0.f, a3 = 0.f;
    #pragma unroll
    for (int c = 0; c < 8; c++) {
        float4 g = gw4[lane * 8 + c];
        a0 += xv[c] * g.x; a1 += xv[c] * g.y; a2 += xv[c] * g.z; a3 += xv[c] * g.w;
    }
    bf16x8 o;
    #pragma unroll
    for (int c = 0; c < 8; c++) o[c] = (bf16_t)xv[c];
    *(bf16x8*)(acat + (size_t)node * K1 + DIM + lane * 8) = o;
    for (int off = 32; off > 0; off >>= 1) {
        a0 += __shfl_xor(a0, off);
        a1 += __shfl_xor(a1, off);
        a2 += __shfl_xor(a2, off);
        a3 += __shfl_xor(a3, off);
    }
    if (lane == 0) {
        float z[4] = { a0 + gb[0], a1 + gb[1], a2 + gb[2], a3 + gb[3] };
        int bi = 0; float bm = z[0];
        for (int e = 1; e < 4; e++) if (z[e] > bm) { bm = z[e]; bi = e; }
        float den = 0.f;
        for (int e = 0; e < 4; e++) den += expf(z[e] - bm);
        top_idx[node] = bi;
        top_val[node] = 1.0f / den;
    }
}

// ---------------- expert bucketing + degree count (fused; r9-proven) ---
__global__ void bucket_deg_kernel(const int* __restrict__ top_idx,
                                  int* __restrict__ ecnt,
                                  int* __restrict__ lists,
                                  const int* __restrict__ dst,
                                  int* __restrict__ deg) {
    const int gi = blockIdx.x * 256 + threadIdx.x;
    if (gi < N_EDGES) atomicAdd(&deg[dst[gi]], 1);

    if (blockIdx.x < 40) {
        __shared__ int lcnt[NEXP];
        __shared__ int base[NEXP];
        const int tid = threadIdx.x;
        if (tid < NEXP) lcnt[tid] = 0;
        __syncthreads();
        const int node = blockIdx.x * 256 + tid;
        int e = 0, rank = 0;
        if (node < N_NODES) {
            e = top_idx[node];
            rank = atomicAdd(&lcnt[e], 1);
        }
        __syncthreads();
        if (tid < NEXP) base[tid] = atomicAdd(&ecnt[tid], lcnt[tid]);
        __syncthreads();
        if (node < N_NODES) lists[e * N_NODES + base[e] + rank] = node;
    }
}

// scan + layer-2 job table (fused; r9-proven)
__global__ void scan_kernel(const int* __restrict__ deg,
                            int* __restrict__ offs,
                            int* __restrict__ cursor,
                            const int* __restrict__ ecnt,
                            int* __restrict__ jobs) {
    __shared__ int wsum[16];
    __shared__ int carrysh;
    const int tid = threadIdx.x;
    const int lane = tid & 63;
    const int wv = tid >> 6;
    if (tid == 0) {
        carrysh = 0;
        int pref = 0;
        for (int e2 = 0; e2 < NEXP; e2++) {
            jobs[e2] = pref;
            pref += (ecnt[e2] + 127) >> 7;
        }
        jobs[4] = pref;
    }
    __syncthreads();
    for (int base = 0; base < N_NODES; base += 1024) {
        int i = base + tid;
        int v = (i < N_NODES) ? deg[i] : 0;
        int s = v;
        #pragma unroll
        for (int off = 1; off < 64; off <<= 1) {
            int t = __shfl_up(s, off);
            if (lane >= off) s += t;
        }
        if (lane == 63) wsum[wv] = s;
        int carry = carrysh;
        __syncthreads();
        if (wv == 0) {
            int w = (lane < 16) ? wsum[lane] : 0;
            #pragma unroll
            for (int off = 1; off < 16; off <<= 1) {
                int t = __shfl_up(w, off);
                if (lane >= off) w += t;
            }
            if (lane < 16) wsum[lane] = w;
        }
        __syncthreads();
        int wbase = (wv > 0) ? wsum[wv - 1] : 0;
        int excl = carry + wbase + s - v;
        if (i < N_NODES) { offs[i] = excl; cursor[i] = excl; }
        int total = wsum[15];
        __syncthreads();
        if (tid == 0) carrysh = carry + total;
        __syncthreads();
    }
    if (tid == 0) offs[N_NODES] = carrysh;
}

// ---------------- CSR fill + weight transpose (fused; r9-proven) ------------
__global__ void fill_wtrans_kernel(const int* __restrict__ src, const int* __restrict__ dst,
                                   int* __restrict__ cursor, int* __restrict__ csr,
                                   const float* __restrict__ w_neigh,
                                   const float* __restrict__ w_self,
                                   bf16_t* __restrict__ Bt) {
    if (blockIdx.x < 625) {
        int i = blockIdx.x * 256 + threadIdx.x;
        if (i < N_EDGES) {
            int d = dst[i];
            int p = atomicAdd(&cursor[d], 1);
            csr[p] = src[i];
        }
    } else {
        __shared__ float tile[32][33];
        const int q = blockIdx.x - 625;
        const int m = q >> 8;
        const bool isSelf = m >= 8;
        const int el = m & 7;
        const float* W = (isSelf ? w_self : w_neigh) + (size_t)el * DIM * DIM;
        const int k0 = (q & 15) * 32;
        const int n0 = ((q >> 4) & 15) * 32;
        const int tx = threadIdx.x & 31, ty = threadIdx.x >> 5;
        for (int r = ty; r < 32; r += 8)
            tile[r][tx] = W[(size_t)(k0 + r) * DIM + n0 + tx];
        __syncthreads();
        for (int r = ty; r < 32; r += 8) {
            int n = n0 + r;
            int k = k0 + tx;
            Bt[((size_t)el * DIM + n) * K1 + (isSelf ? DIM : 0) + k] = (bf16_t)tile[tx][r];
        }
    }
}

// ---------------- agg1: mean of x rows into acat cols 0..511, unroll 8 ----------------
__global__ void agg1_kernel(const int* __restrict__ offs, const int* __restrict__ csr,
                            bf16_t* __restrict__ acat) {
    const int wave = threadIdx.x >> 6;
    const int lane = threadIdx.x & 63;
    const int node = blockIdx.x * 4 + wave;
    if (node >= N_NODES) return;
    const int c0 = lane * 8;
    float s[8] = {0,0,0,0,0,0,0,0};
    int beg = offs[node];
    int end = offs[node + 1];
    int d = end - beg;
    int p = beg;
    for (; p + 8 <= end; p += 8) {
        bf16x8 v[8];
        #pragma unroll
        for (int q = 0; q < 8; q++) {
            int idx = csr[p + q];
            v[q] = *(const bf16x8*)(acat + (size_t)idx * K1 + DIM + c0);
        }
        #pragma unroll
        for (int q = 0; q < 8; q++)
            #pragma unroll
            for (int k = 0; k < 8; k++) s[k] += (float)v[q][k];
    }
    for (; p + 4 <= end; p += 4) {
        bf16x8 v[4];
        #pragma unroll
        for (int q = 0; q < 4; q++) {
            int idx = csr[p + q];
            v[q] = *(const bf16x8*)(acat + (size_t)idx * K1 + DIM + c0);
        }
        #pragma unroll
        for (int q = 0; q < 4; q++)
            #pragma unroll
            for (int k = 0; k < 8; k++) s[k] += (float)v[q][k];
    }
    for (; p < end; p++) {
        int idx = csr[p];
        bf16x8 v0 = *(const bf16x8*)(acat + (size_t)idx * K1 + DIM + c0);
        #pragma unroll
        for (int k = 0; k < 8; k++) s[k] += (float)v0[k];
    }
    float w = d > 0 ? 1.0f / (float)d : 0.0f;
    bf16x8 o;
    #pragma unroll
    for (int k = 0; k < 8; k++) o[k] = (bf16_t)(s[k] * w);
    *(bf16x8*)(acat + (size_t)node * K1 + c0) = o;
}

// ---------------- agg2: selected-expert mean of h1 rows + self copy, unroll 8 ----------------
__global__ void agg2_kernel(const int* __restrict__ offs, const int* __restrict__ csr,
                            const int* __restrict__ top_idx,
                            const bf16_t* __restrict__ h1, bf16_t* __restrict__ acat) {
    const int wave = threadIdx.x >> 6;
    const int lane = threadIdx.x & 63;
    const int node = blockIdx.x * 4 + wave;
    if (node >= N_NODES) return;
    const int c0 = lane * 8;
    const bf16_t* hb = h1 + (size_t)top_idx[node] * N_NODES * DIM;
    float s[8] = {0,0,0,0,0,0,0,0};
    int beg = offs[node];
    int end = offs[node + 1];
    int d = end - beg;
    int p = beg;
    for (; p + 8 <= end; p += 8) {
        bf16x8 v[8];
        #pragma unroll
        for (int q = 0; q < 8; q++) {
            int idx = csr[p + q];
            v[q] = *(const bf16x8*)(hb + (size_t)idx * DIM + c0);
        }
        #pragma unroll
        for (int q = 0; q < 8; q++)
            #pragma unroll
            for (int k = 0; k < 8; k++) s[k] += (float)v[q][k];
    }
    for (; p + 4 <= end; p += 4) {
        bf16x8 v[4];
        #pragma unroll
        for (int q = 0; q < 4; q++) {
            int idx = csr[p + q];
            v[q] = *(const bf16x8*)(hb + (size_t)idx * DIM + c0);
        }
        #pragma unroll
        for (int q = 0; q < 4; q++)
            #pragma unroll
            for (int k = 0; k < 8; k++) s[k] += (float)v[q][k];
    }
    for (; p < end; p++) {
        int idx = csr[p];
        bf16x8 v0 = *(const bf16x8*)(hb + (size_t)idx * DIM + c0);
        #pragma unroll
        for (int k = 0; k < 8; k++) s[k] += (float)v0[k];
    }
    float w = d > 0 ? 1.0f / (float)d : 0.0f;
    bf16x8 o;
    #pragma unroll
    for (int k = 0; k < 8; k++) o[k] = (bf16_t)(s[k] * w);
    *(bf16x8*)(acat + (size_t)node * K1 + c0) = o;
    *(bf16x8*)(acat + (size_t)node * K1 + DIM + c0) = *(const bf16x8*)(hb + (size_t)node * DIM + c0);
}

// ---------------- layer-1 GEMM: 640x128, 3-phase schedule, 4 barriers/tile (r8) -----
// FINAL: best measured variant (50.8-54 us, MfmaUtil ~33%). Variants r3/r4/r9/r12
// (53/57.5/53.4/81) all confirmed this as the fixed point.
__global__ __launch_bounds__(512, 2)
void gemm_l1_kernel(const bf16_t* __restrict__ A,
                    const bf16_t* __restrict__ Bt,
                    const float* __restrict__ bias_all,
                    bf16_t* __restrict__ h1) {
    const int b = blockIdx.x;
    const int xcd = b & 7;
    const int loc = b >> 3;
    const int mtile = xcd * 2 + (loc >> 4);
    const int ntile = loc & 15;
    const int e = ntile >> 2;

    __shared__ __align__(16) bf16_t As[3 * 640 * 32];
    __shared__ __align__(16) bf16_t Bs[3 * 128 * 32];

    const int t = threadIdx.x;
    const int lane = t & 63;
    const int wave = t >> 6;
    const int rloc = t >> 2;
    const int cgl = ((t & 3) - ((t >> 3) & 3)) & 3;

    const bf16_t* pA0 = A + (size_t)min(mtile * 640 +   0 + rloc, N_NODES - 1) * K1 + cgl * 8;
    const bf16_t* pA1 = A + (size_t)min(mtile * 640 + 128 + rloc, N_NODES - 1) * K1 + cgl * 8;
    const bf16_t* pA2 = A + (size_t)min(mtile * 640 + 256 + rloc, N_NODES - 1) * K1 + cgl * 8;
    const bf16_t* pA3 = A + (size_t)min(mtile * 640 + 384 + rloc, N_NODES - 1) * K1 + cgl * 8;
    const bf16_t* pA4 = A + (size_t)min(mtile * 640 + 512 + rloc, N_NODES - 1) * K1 + cgl * 8;
    const bf16_t* pB0 = Bt + ((size_t)(e * 2 + 0) * DIM + (ntile & 3) * 128 + rloc) * K1 + cgl * 8;

    char* asb = (char*)&As[0];
    char* bsb = (char*)&Bs[0];

    auto stage_full = [&](int bu) {
        char* ab = asb + bu * 40960 + wave * 1024;
        char* bb = bsb + bu * 8192  + wave * 1024;
        __builtin_amdgcn_global_load_lds(AS1(pA0), AS3(ab),          16, 0, 0);
        __builtin_amdgcn_global_load_lds(AS1(pA1), AS3(ab + 8192),   16, 0, 0);
        __builtin_amdgcn_global_load_lds(AS1(pA2), AS3(ab + 16384),  16, 0, 0);
        __builtin_amdgcn_global_load_lds(AS1(pA3), AS3(ab + 24576),  16, 0, 0);
        __builtin_amdgcn_global_load_lds(AS1(pA4), AS3(ab + 32768),  16, 0, 0);
        __builtin_amdgcn_global_load_lds(AS1(pB0), AS3(bb),          16, 0, 0);
        pA0 += 32; pA1 += 32; pA2 += 32; pA3 += 32; pA4 += 32; pB0 += 32;
    };

    const int rfr = lane & 15;
    const int cpr = lane >> 4;
    const int wm = wave >> 1;
    const int wn = wave & 1;
    const int arow = wm * 160 + rfr;
    const int brow = wn * 64 + rfr;
    const int ppA = (cpr + (arow >> 1)) & 3;
    const int ppB = (cpr + (brow >> 1)) & 3;
    const int aoff = arow * 32 + ppA * 8;
    const int boff = brow * 32 + ppB * 8;

    f32x4 acc[10][4] = {};

    auto compute_full = [&](int bu) {
        const bf16_t* Ab = As + bu * 20480 + aoff;
        const bf16_t* Bb = Bs + bu * 4096  + boff;
        bf16x8 bfr[4];
        #pragma unroll
        for (int j = 0; j < 4; j++) bfr[j] = *(const bf16x8*)(Bb + j * 512);
        #pragma unroll
        for (int i = 0; i < 10; i++) {
            bf16x8 af = *(const bf16x8*)(Ab + i * 512);
            #pragma unroll
            for (int j = 0; j < 4; j++)
                MFMA16(acc[i][j], af, bfr[j]);
        }
    };

    stage_full(0);
    stage_full(1);

    int cb = 0, sb = 2;
    for (int tt = 0; tt < 31; ++tt) {
        VMW(6);
        __builtin_amdgcn_s_barrier();
        asm volatile("" ::: "memory");
        const bool st = (tt < 30);
        char* ab = asb + sb * 40960 + wave * 1024;
        char* bb = bsb + sb * 8192  + wave * 1024;
        const bf16_t* Ab = As + cb * 20480 + aoff;
        const bf16_t* Bb = Bs + cb * 4096  + boff;

        bf16x8 bq[4], aq[4];

        #pragma unroll
        for (int j = 0; j < 4; j++) bq[j] = *(const bf16x8*)(Bb + j * 512);
        #pragma unroll
        for (int i = 0; i < 4; i++) aq[i] = *(const bf16x8*)(Ab + i * 512);
        if (st) {
            __builtin_amdgcn_global_load_lds(AS1(pA0), AS3(ab),        16, 0, 0);
            __builtin_amdgcn_global_load_lds(AS1(pA1), AS3(ab + 8192), 16, 0, 0);
        }
        __builtin_amdgcn_s_barrier();
        asm volatile("s_waitcnt lgkmcnt(0)" ::: "memory");
        __builtin_amdgcn_sched_barrier(0);
        __builtin_amdgcn_s_setprio(1);
        #pragma unroll
        for (int i = 0; i < 4; i++)
            #pragma unroll
            for (int j = 0; j < 4; j++)
                MFMA16(acc[i][j], aq[i], bq[j]);
        __builtin_amdgcn_s_setprio(0);

        #pragma unroll
        for (int i = 0; i < 3; i++) aq[i] = *(const bf16x8*)(Ab + (4 + i) * 512);
        if (st) {
            __builtin_amdgcn_global_load_lds(AS1(pA2), AS3(ab + 16384), 16, 0, 0);
            __builtin_amdgcn_global_load_lds(AS1(pA3), AS3(ab + 24576), 16, 0, 0);
        }
        __builtin_amdgcn_s_barrier();
        asm volatile("s_waitcnt lgkmcnt(0)" ::: "memory");
        __builtin_amdgcn_sched_barrier(0);
        __builtin_amdgcn_s_setprio(1);
        #pragma unroll
        for (int i = 0; i < 3; i++)
            #pragma unroll
            for (int j = 0; j < 4; j++)
                MFMA16(acc[4 + i][j], aq[i], bq[j]);
        __builtin_amdgcn_s_setprio(0);

        #pragma unroll
        for (int i = 0; i < 3; i++) aq[i] = *(const bf16x8*)(Ab + (7 + i) * 512);
        if (st) {
            __builtin_amdgcn_global_load_lds(AS1(pA4), AS3(ab + 32768), 16, 0, 0);
            __builtin_amdgcn_global_load_lds(AS1(pB0), AS3(bb),         16, 0, 0);
        }
        __builtin_amdgcn_s_barrier();
        asm volatile("s_waitcnt lgkmcnt(0)" ::: "memory");
        __builtin_amdgcn_sched_barrier(0);
        __builtin_amdgcn_s_setprio(1);
        #pragma unroll
        for (int i = 0; i < 3; i++)
            #pragma unroll
            for (int j = 0; j < 4; j++)
                MFMA16(acc[7 + i][j], aq[i], bq[j]);
        __builtin_amdgcn_s_setprio(0);

        if (st) {
            pA0 += 32; pA1 += 32; pA2 += 32; pA3 += 32; pA4 += 32; pB0 += 32;
            sb = (sb == 2) ? 0 : sb + 1;
        }
        cb = (cb == 2) ? 0 : cb + 1;
    }
    VMW(0);
    __builtin_amdgcn_s_barrier();
    asm volatile("" ::: "memory");
    compute_full(cb);

    const float* bias = bias_all + e * 1024;
    const int cobase = (ntile & 3) * 128 + wn * 64 + (lane & 15);
    float bv[4];
    #pragma unroll
    for (int j = 0; j < 4; j++) bv[j] = bias[cobase + j * 16];
    const int rbase = mtile * 640 + wm * 160 + (lane >> 4) * 4;
    #pragma unroll
    for (int i = 0; i < 10; i++) {
        #pragma unroll
        for (int r = 0; r < 4; r++) {
            int row = rbase + i * 16 + r;
            if (row < N_NODES) {
                bf16_t* cp = h1 + ((size_t)e * N_NODES + row) * DIM + cobase;
                #pragma unroll
                for (int j = 0; j < 4; j++) {
                    float v = fmaxf(acc[i][j][r] + bv[j], 0.f);
                    cp[j * 16] = (bf16_t)v;
                }
            }
        }
    }
}

// ---------------- layer-2 GEMM: compact jobs + pipelined K-loop ---------
// r14: grid 320 -> 512. total = 4*sum(ceil(cnt_e/128)); with cnt_e ~ 2500+-sigma
// (deterministic seed), any expert > 2560 nodes makes total = 324..336 > 320, forcing
// some blocks to grid-stride a SECOND job while the rest idle -> gemm2 makespan x2.
// 512 blocks guarantees <= 1 job/block for any plausible total; surplus blocks read
// jobs[4], skip the loop (zero barriers), exit. Body unchanged (r7-proven).
__global__ __launch_bounds__(256)
void gemm2_kernel(const bf16_t* __restrict__ A,
                  const bf16_t* __restrict__ Bt,
                  const float* __restrict__ bias_all,
                  float* __restrict__ out,
                  const int* __restrict__ lists,
                  const int* __restrict__ ecnt,
                  const int* __restrict__ jobs,
                  const float* __restrict__ top_val) {
    __shared__ __align__(16) bf16_t As[3 * 128 * 32];
    __shared__ __align__(16) bf16_t Bs[3 * 128 * 32];

    const int t = threadIdx.x;
    const int lane = t & 63;
    const int wave = t >> 6;
    const int wm = wave >> 1;
    const int wn = wave & 1;
    const int r0 = t >> 2;
    const int rot = (t >> 3) & 3;
    const int cgl = ((t & 3) - rot) & 3;
    const int cpr = lane >> 4;
    const int rfr = lane & 15;
    char* asb = (char*)&As[0];
    char* bsb = (char*)&Bs[0];
    const int wb = wave * 1024;

    const int total = jobs[4] * 4;

    for (int j = blockIdx.x; j < total; j += gridDim.x) {
        const int byt = j >> 2;
        const int bx = j & 3;
        const int e = (byt >= jobs[1]) + (byt >= jobs[2]) + (byt >= jobs[3]);
        const int by = byt - jobs[e];
        const int cnt = ecnt[e];
        const int cmax = max(cnt, 1);

        int i0 = by * 128 + r0;
        int i1 = i0 + 64;
        int arow0 = lists[e * N_NODES + min(i0, cmax - 1)];
        int arow1 = lists[e * N_NODES + min(i1, cmax - 1)];
        arow0 = min(max(arow0, 0), N_NODES - 1);
        arow1 = min(max(arow1, 0), N_NODES - 1);
        const bf16_t* Bte = Bt + (size_t)(e * 2 + 1) * DIM * K1;
        const bf16_t* aptr0 = A + (size_t)arow0 * K1 + cgl * 8;
        const bf16_t* aptr1 = A + (size_t)arow1 * K1 + cgl * 8;
        const bf16_t* bptr0 = Bte + (size_t)(bx * 128 + r0) * K1 + cgl * 8;
        const bf16_t* bptr1 = bptr0 + (size_t)64 * K1;

        f32x4 acc[4][4] = {};

        auto stage = [&](int bu) {
            char* ab = asb + bu * 8192 + wb;
            char* bb = bsb + bu * 8192 + wb;
            __builtin_amdgcn_global_load_lds(AS1(aptr0), AS3(ab),        16, 0, 0);
            __builtin_amdgcn_global_load_lds(AS1(aptr1), AS3(ab + 4096), 16, 0, 0);
            __builtin_amdgcn_global_load_lds(AS1(bptr0), AS3(bb),        16, 0, 0);
            __builtin_amdgcn_global_load_lds(AS1(bptr1), AS3(bb + 4096), 16, 0, 0);
            aptr0 += 32; aptr1 += 32; bptr0 += 32; bptr1 += 32;
        };

        auto compute = [&](int bu) {
            const bf16_t* Ab = As + bu * 4096;
            const bf16_t* Bb = Bs + bu * 4096;
            bf16x8 af[4], bfr[4];
            #pragma unroll
            for (int i = 0; i < 4; i++) {
                int r_full = wm * 64 + i * 16 + rfr;
                int p = (cpr + (r_full >> 1)) & 3;
                af[i] = *(const bf16x8*)(Ab + r_full * 32 + p * 8);
            }
            #pragma unroll
            for (int jj = 0; jj < 4; jj++) {
                int r_full = wn * 64 + jj * 16 + rfr;
                int p = (cpr + (r_full >> 1)) & 3;
                bfr[jj] = *(const bf16x8*)(Bb + r_full * 32 + p * 8);
            }
            #pragma unroll
            for (int i = 0; i < 4; i++)
                #pragma unroll
                for (int jj = 0; jj < 4; jj++)
                    MFMA16(acc[i][jj], af[i], bfr[jj]);
        };

        __builtin_amdgcn_s_barrier();
        asm volatile("" ::: "memory");

        stage(0);
        stage(1);
        int cb = 0, sb = 2;
        for (int tt = 0; tt < 31; ++tt) {
            VMW(4);
            __builtin_amdgcn_s_barrier();
            asm volatile("" ::: "memory");
            if (tt < 30) {
                stage(sb);
                sb = (sb == 2) ? 0 : sb + 1;
            }
            compute(cb);
            cb = (cb == 2) ? 0 : cb + 1;
        }
        VMW(0);
        __builtin_amdgcn_s_barrier();
        asm volatile("" ::: "memory");
        compute(cb);

        const float* bias = bias_all + e * 1024 + DIM;
        const int cbase = bx * 128 + wn * 64 + (lane & 15);
        float bv[4];
        #pragma unroll
        for (int jj = 0; jj < 4; jj++) bv[jj] = bias[cbase + jj * 16];
        #pragma unroll
        for (int i = 0; i < 4; i++) {
            #pragma unroll
            for (int r = 0; r < 4; r++) {
                int row = by * 128 + wm * 64 + i * 16 + (lane >> 4) * 4 + r;
                if (row < cnt) {
                    int node = lists[e * N_NODES + row];
                    float tv = top_val[node];
                    float* cp = out + (size_t)node * DIM + cbase;
                    #pragma unroll
                    for (int jj = 0; jj < 4; jj++) {
                        float v = fmaxf(acc[i][jj][r] + bv[jj], 0.f);
                        cp[jj * 16] = v * tv;
                    }
                }
            }
        }
    }
}

extern "C" void kernel_launch(void* const* d_in, const int* in_sizes, int n_in,
                              void* d_out, int out_size, void* d_ws, size_t ws_size,
                              hipStream_t stream) {
    const float* x       = (const float*)d_in[0];
    const int*   edge    = (const int*)d_in[1];
    const float* gw      = (const float*)d_in[2];
    const float* gb      = (const float*)d_in[3];
    const float* w_self  = (const float*)d_in[4];
    const float* w_neigh = (const float*)d_in[5];
    const float* b_exp   = (const float*)d_in[6];
    float* out = (float*)d_out;

    char* p = (char*)d_ws;
    auto alloc = [&](size_t bytes) {
        char* r = p;
        p += (bytes + 255) & ~(size_t)255;
        return r;
    };
    bf16_t* Bt      = (bf16_t*)alloc((size_t)8 * DIM * K1 * 2);
    bf16_t* acat    = (bf16_t*)alloc((size_t)N_NODES * K1 * 2);
    bf16_t* h1      = (bf16_t*)alloc((size_t)NEXP * N_NODES * DIM * 2);
    int*    deg     = (int*)alloc((size_t)N_NODES * 4);
    int*    offs    = (int*)alloc((size_t)(N_NODES + 1) * 4);
    int*    cursor  = (int*)alloc((size_t)N_NODES * 4);
    int*    csr     = (int*)alloc((size_t)N_EDGES * 4);
    int*    top_idx = (int*)alloc((size_t)N_NODES * 4);
    float*  top_val = (float*)alloc((size_t)N_NODES * 4);
    int*    ecnt    = (int*)alloc(256);
    int*    lists   = (int*)alloc((size_t)NEXP * N_NODES * 4);
    int*    jobs    = ecnt + 8;

    const int* srcE = edge;
    const int* dstE = edge + N_EDGES;

    gate_kernel<<<N_NODES / 4, 256, 0, stream>>>(x, gw, gb, top_idx, top_val, acat, deg, ecnt);
    bucket_deg_kernel<<<N_EDGES / 256, 256, 0, stream>>>(top_idx, ecnt, lists, dstE, deg);
    scan_kernel<<<1, 1024, 0, stream>>>(deg, offs, cursor, ecnt, jobs);
    fill_wtrans_kernel<<<625 + 4096, 256, 0, stream>>>(srcE, dstE, cursor, csr, w_neigh, w_self, Bt);
    agg1_kernel<<<N_NODES / 4, 256, 0, stream>>>(offs, csr, acat);
    gemm_l1_kernel<<<256, 512, 0, stream>>>(acat, Bt, b_exp, h1);
    agg2_kernel<<<N_NODES / 4, 256, 0, stream>>>(offs, csr, top_idx, h1, acat);
    gemm2_kernel<<<512, 256, 0, stream>>>(acat, Bt, b_exp, out, lists, ecnt, jobs, top_val);
}

// Round 15
// 261.977 us; speedup vs baseline: 1.1301x; 1.0056x over previous
//
#include <hip/hip_runtime.h>
#include <hip/hip_bf16.h>
#include <cstdint>

#define N_NODES 10000
#define N_EDGES 160000
#define DIM 512
#define K1 1024
#define NEXP 4

typedef __bf16 bf16_t;
typedef bf16_t bf16x8 __attribute__((ext_vector_type(8)));
typedef float f32x4 __attribute__((ext_vector_type(4)));

#define AS1(p) ((__attribute__((address_space(1))) void*)(p))
#define AS3(p) ((__attribute__((address_space(3))) void*)(p))

#define VMW(N) asm volatile("s_waitcnt vmcnt(" #N ")" ::: "memory")
#define MFMA16(d, a_, b_) d = __builtin_amdgcn_mfma_f32_16x16x32_bf16(a_, b_, d, 0, 0, 0)

// ---------------- gating + x->bf16 + counter zeroing (fused; r9-proven) ---------
__global__ void gate_kernel(const float* __restrict__ x,
                            const float* __restrict__ gw,
                            const float* __restrict__ gb,
                            int* __restrict__ top_idx,
                            float* __restrict__ top_val,
                            bf16_t* __restrict__ acat,
                            int* __restrict__ deg,
                            int* __restrict__ ecnt) {
    const int gid = blockIdx.x * 256 + threadIdx.x;
    if (gid < N_NODES) deg[gid] = 0;
    if (gid < NEXP) ecnt[gid] = 0;

    const int wave = threadIdx.x >> 6;
    const int lane = threadIdx.x & 63;
    const int node = blockIdx.x * 4 + wave;
    if (node >= N_NODES) return;
    const float4* x4 = (const float4*)(x + (size_t)node * DIM);
    const float4* gw4 = (const float4*)gw;
    float4 xa = x4[lane * 2];
    float4 xb = x4[lane * 2 + 1];
    float xv[8] = { xa.x, xa.y, xa.z, xa.w, xb.x, xb.y, xb.z, xb.w };
    float a0 = 0.f, a1 = 0.f, a2 = 0.f, a3 = 0.f;
    #pragma unroll
    for (int c = 0; c < 8; c++) {
        float4 g = gw4[lane * 8 + c];
        a0 += xv[c] * g.x; a1 += xv[c] * g.y; a2 += xv[c] * g.z; a3 += xv[c] * g.w;
    }
    bf16x8 o;
    #pragma unroll
    for (int c = 0; c < 8; c++) o[c] = (bf16_t)xv[c];
    *(bf16x8*)(acat + (size_t)node * K1 + DIM + lane * 8) = o;
    for (int off = 32; off > 0; off >>= 1) {
        a0 += __shfl_xor(a0, off);
        a1 += __shfl_xor(a1, off);
        a2 += __shfl_xor(a2, off);
        a3 += __shfl_xor(a3, off);
    }
    if (lane == 0) {
        float z[4] = { a0 + gb[0], a1 + gb[1], a2 + gb[2], a3 + gb[3] };
        int bi = 0; float bm = z[0];
        for (int e = 1; e < 4; e++) if (z[e] > bm) { bm = z[e]; bi = e; }
        float den = 0.f;
        for (int e = 0; e < 4; e++) den += expf(z[e] - bm);
        top_idx[node] = bi;
        top_val[node] = 1.0f / den;
    }
}

// ---------------- expert bucketing + degree count (fused; r9-proven) ---
__global__ void bucket_deg_kernel(const int* __restrict__ top_idx,
                                  int* __restrict__ ecnt,
                                  int* __restrict__ lists,
                                  const int* __restrict__ dst,
                                  int* __restrict__ deg) {
    const int gi = blockIdx.x * 256 + threadIdx.x;
    if (gi < N_EDGES) atomicAdd(&deg[dst[gi]], 1);

    if (blockIdx.x < 40) {
        __shared__ int lcnt[NEXP];
        __shared__ int base[NEXP];
        const int tid = threadIdx.x;
        if (tid < NEXP) lcnt[tid] = 0;
        __syncthreads();
        const int node = blockIdx.x * 256 + tid;
        int e = 0, rank = 0;
        if (node < N_NODES) {
            e = top_idx[node];
            rank = atomicAdd(&lcnt[e], 1);
        }
        __syncthreads();
        if (tid < NEXP) base[tid] = atomicAdd(&ecnt[tid], lcnt[tid]);
        __syncthreads();
        if (node < N_NODES) lists[e * N_NODES + base[e] + rank] = node;
    }
}

// scan + layer-2 job table. r15: preload all 10 chunks + wave-scans into registers
// up front (independent loads, latency overlapped once) -> the serial carry chain is
// LDS/barrier-only (~400 cyc/iter) instead of paying a global-load round trip per
// iteration on a single resident block. Ordering semantics identical to r9 version.
__global__ void scan_kernel(const int* __restrict__ deg,
                            int* __restrict__ offs,
                            int* __restrict__ cursor,
                            const int* __restrict__ ecnt,
                            int* __restrict__ jobs) {
    __shared__ int wsum[16];
    __shared__ int carrysh;
    const int tid = threadIdx.x;
    const int lane = tid & 63;
    const int wv = tid >> 6;
    if (tid == 0) {
        carrysh = 0;
        int pref = 0;
        for (int e2 = 0; e2 < NEXP; e2++) {
            jobs[e2] = pref;
            pref += (ecnt[e2] + 127) >> 7;
        }
        jobs[4] = pref;
    }
    // preload + per-wave inclusive scan, all chunks, register-resident
    int v[10], s[10];
    #pragma unroll
    for (int k = 0; k < 10; k++) {
        int i = k * 1024 + tid;
        v[k] = (i < N_NODES) ? deg[i] : 0;
        int sv = v[k];
        #pragma unroll
        for (int off = 1; off < 64; off <<= 1) {
            int t2 = __shfl_up(sv, off);
            if (lane >= off) sv += t2;
        }
        s[k] = sv;
    }
    __syncthreads();          // carrysh=0 visible; preload done
    #pragma unroll
    for (int k = 0; k < 10; k++) {
        if (lane == 63) wsum[wv] = s[k];
        int carry = carrysh;
        __syncthreads();
        if (wv == 0) {
            int w = (lane < 16) ? wsum[lane] : 0;
            #pragma unroll
            for (int off = 1; off < 16; off <<= 1) {
                int t2 = __shfl_up(w, off);
                if (lane >= off) w += t2;
            }
            if (lane < 16) wsum[lane] = w;
        }
        __syncthreads();
        int wbase = (wv > 0) ? wsum[wv - 1] : 0;
        int excl = carry + wbase + s[k] - v[k];
        int i = k * 1024 + tid;
        if (i < N_NODES) { offs[i] = excl; cursor[i] = excl; }
        int total = wsum[15];
        __syncthreads();
        if (tid == 0) carrysh = carry + total;
        __syncthreads();
    }
    if (tid == 0) offs[N_NODES] = carrysh;
}

// ---------------- CSR fill + weight transpose (fused; r9-proven) ------------
__global__ void fill_wtrans_kernel(const int* __restrict__ src, const int* __restrict__ dst,
                                   int* __restrict__ cursor, int* __restrict__ csr,
                                   const float* __restrict__ w_neigh,
                                   const float* __restrict__ w_self,
                                   bf16_t* __restrict__ Bt) {
    if (blockIdx.x < 625) {
        int i = blockIdx.x * 256 + threadIdx.x;
        if (i < N_EDGES) {
            int d = dst[i];
            int p = atomicAdd(&cursor[d], 1);
            csr[p] = src[i];
        }
    } else {
        __shared__ float tile[32][33];
        const int q = blockIdx.x - 625;
        const int m = q >> 8;
        const bool isSelf = m >= 8;
        const int el = m & 7;
        const float* W = (isSelf ? w_self : w_neigh) + (size_t)el * DIM * DIM;
        const int k0 = (q & 15) * 32;
        const int n0 = ((q >> 4) & 15) * 32;
        const int tx = threadIdx.x & 31, ty = threadIdx.x >> 5;
        for (int r = ty; r < 32; r += 8)
            tile[r][tx] = W[(size_t)(k0 + r) * DIM + n0 + tx];
        __syncthreads();
        for (int r = ty; r < 32; r += 8) {
            int n = n0 + r;
            int k = k0 + tx;
            Bt[((size_t)el * DIM + n) * K1 + (isSelf ? DIM : 0) + k] = (bf16_t)tile[tx][r];
        }
    }
}

// ---------------- agg1: mean of x rows into acat cols 0..511, unroll 8 ----------------
__global__ void agg1_kernel(const int* __restrict__ offs, const int* __restrict__ csr,
                            bf16_t* __restrict__ acat) {
    const int wave = threadIdx.x >> 6;
    const int lane = threadIdx.x & 63;
    const int node = blockIdx.x * 4 + wave;
    if (node >= N_NODES) return;
    const int c0 = lane * 8;
    float s[8] = {0,0,0,0,0,0,0,0};
    int beg = offs[node];
    int end = offs[node + 1];
    int d = end - beg;
    int p = beg;
    for (; p + 8 <= end; p += 8) {
        bf16x8 v[8];
        #pragma unroll
        for (int q = 0; q < 8; q++) {
            int idx = csr[p + q];
            v[q] = *(const bf16x8*)(acat + (size_t)idx * K1 + DIM + c0);
        }
        #pragma unroll
        for (int q = 0; q < 8; q++)
            #pragma unroll
            for (int k = 0; k < 8; k++) s[k] += (float)v[q][k];
    }
    for (; p + 4 <= end; p += 4) {
        bf16x8 v[4];
        #pragma unroll
        for (int q = 0; q < 4; q++) {
            int idx = csr[p + q];
            v[q] = *(const bf16x8*)(acat + (size_t)idx * K1 + DIM + c0);
        }
        #pragma unroll
        for (int q = 0; q < 4; q++)
            #pragma unroll
            for (int k = 0; k < 8; k++) s[k] += (float)v[q][k];
    }
    for (; p < end; p++) {
        int idx = csr[p];
        bf16x8 v0 = *(const bf16x8*)(acat + (size_t)idx * K1 + DIM + c0);
        #pragma unroll
        for (int k = 0; k < 8; k++) s[k] += (float)v0[k];
    }
    float w = d > 0 ? 1.0f / (float)d : 0.0f;
    bf16x8 o;
    #pragma unroll
    for (int k = 0; k < 8; k++) o[k] = (bf16_t)(s[k] * w);
    *(bf16x8*)(acat + (size_t)node * K1 + c0) = o;
}

// ---------------- agg2: selected-expert mean of h1 rows + self copy, unroll 8 ----------------
__global__ void agg2_kernel(const int* __restrict__ offs, const int* __restrict__ csr,
                            const int* __restrict__ top_idx,
                            const bf16_t* __restrict__ h1, bf16_t* __restrict__ acat) {
    const int wave = threadIdx.x >> 6;
    const int lane = threadIdx.x & 63;
    const int node = blockIdx.x * 4 + wave;
    if (node >= N_NODES) return;
    const int c0 = lane * 8;
    const bf16_t* hb = h1 + (size_t)top_idx[node] * N_NODES * DIM;
    float s[8] = {0,0,0,0,0,0,0,0};
    int beg = offs[node];
    int end = offs[node + 1];
    int d = end - beg;
    int p = beg;
    for (; p + 8 <= end; p += 8) {
        bf16x8 v[8];
        #pragma unroll
        for (int q = 0; q < 8; q++) {
            int idx = csr[p + q];
            v[q] = *(const bf16x8*)(hb + (size_t)idx * DIM + c0);
        }
        #pragma unroll
        for (int q = 0; q < 8; q++)
            #pragma unroll
            for (int k = 0; k < 8; k++) s[k] += (float)v[q][k];
    }
    for (; p + 4 <= end; p += 4) {
        bf16x8 v[4];
        #pragma unroll
        for (int q = 0; q < 4; q++) {
            int idx = csr[p + q];
            v[q] = *(const bf16x8*)(hb + (size_t)idx * DIM + c0);
        }
        #pragma unroll
        for (int q = 0; q < 4; q++)
            #pragma unroll
            for (int k = 0; k < 8; k++) s[k] += (float)v[q][k];
    }
    for (; p < end; p++) {
        int idx = csr[p];
        bf16x8 v0 = *(const bf16x8*)(hb + (size_t)idx * DIM + c0);
        #pragma unroll
        for (int k = 0; k < 8; k++) s[k] += (float)v0[k];
    }
    float w = d > 0 ? 1.0f / (float)d : 0.0f;
    bf16x8 o;
    #pragma unroll
    for (int k = 0; k < 8; k++) o[k] = (bf16_t)(s[k] * w);
    *(bf16x8*)(acat + (size_t)node * K1 + c0) = o;
    *(bf16x8*)(acat + (size_t)node * K1 + DIM + c0) = *(const bf16x8*)(hb + (size_t)node * DIM + c0);
}

// ---------------- layer-1 GEMM: 640x128, 3-phase schedule, 4 barriers/tile (r8) -----
// FINAL: best measured variant (50.8-51 us, MfmaUtil ~32%). Six variants confirmed
// this as the structural fixed point for this shape.
__global__ __launch_bounds__(512, 2)
void gemm_l1_kernel(const bf16_t* __restrict__ A,
                    const bf16_t* __restrict__ Bt,
                    const float* __restrict__ bias_all,
                    bf16_t* __restrict__ h1) {
    const int b = blockIdx.x;
    const int xcd = b & 7;
    const int loc = b >> 3;
    const int mtile = xcd * 2 + (loc >> 4);
    const int ntile = loc & 15;
    const int e = ntile >> 2;

    __shared__ __align__(16) bf16_t As[3 * 640 * 32];
    __shared__ __align__(16) bf16_t Bs[3 * 128 * 32];

    const int t = threadIdx.x;
    const int lane = t & 63;
    const int wave = t >> 6;
    const int rloc = t >> 2;
    const int cgl = ((t & 3) - ((t >> 3) & 3)) & 3;

    const bf16_t* pA0 = A + (size_t)min(mtile * 640 +   0 + rloc, N_NODES - 1) * K1 + cgl * 8;
    const bf16_t* pA1 = A + (size_t)min(mtile * 640 + 128 + rloc, N_NODES - 1) * K1 + cgl * 8;
    const bf16_t* pA2 = A + (size_t)min(mtile * 640 + 256 + rloc, N_NODES - 1) * K1 + cgl * 8;
    const bf16_t* pA3 = A + (size_t)min(mtile * 640 + 384 + rloc, N_NODES - 1) * K1 + cgl * 8;
    const bf16_t* pA4 = A + (size_t)min(mtile * 640 + 512 + rloc, N_NODES - 1) * K1 + cgl * 8;
    const bf16_t* pB0 = Bt + ((size_t)(e * 2 + 0) * DIM + (ntile & 3) * 128 + rloc) * K1 + cgl * 8;

    char* asb = (char*)&As[0];
    char* bsb = (char*)&Bs[0];

    auto stage_full = [&](int bu) {
        char* ab = asb + bu * 40960 + wave * 1024;
        char* bb = bsb + bu * 8192  + wave * 1024;
        __builtin_amdgcn_global_load_lds(AS1(pA0), AS3(ab),          16, 0, 0);
        __builtin_amdgcn_global_load_lds(AS1(pA1), AS3(ab + 8192),   16, 0, 0);
        __builtin_amdgcn_global_load_lds(AS1(pA2), AS3(ab + 16384),  16, 0, 0);
        __builtin_amdgcn_global_load_lds(AS1(pA3), AS3(ab + 24576),  16, 0, 0);
        __builtin_amdgcn_global_load_lds(AS1(pA4), AS3(ab + 32768),  16, 0, 0);
        __builtin_amdgcn_global_load_lds(AS1(pB0), AS3(bb),          16, 0, 0);
        pA0 += 32; pA1 += 32; pA2 += 32; pA3 += 32; pA4 += 32; pB0 += 32;
    };

    const int rfr = lane & 15;
    const int cpr = lane >> 4;
    const int wm = wave >> 1;
    const int wn = wave & 1;
    const int arow = wm * 160 + rfr;
    const int brow = wn * 64 + rfr;
    const int ppA = (cpr + (arow >> 1)) & 3;
    const int ppB = (cpr + (brow >> 1)) & 3;
    const int aoff = arow * 32 + ppA * 8;
    const int boff = brow * 32 + ppB * 8;

    f32x4 acc[10][4] = {};

    auto compute_full = [&](int bu) {
        const bf16_t* Ab = As + bu * 20480 + aoff;
        const bf16_t* Bb = Bs + bu * 4096  + boff;
        bf16x8 bfr[4];
        #pragma unroll
        for (int j = 0; j < 4; j++) bfr[j] = *(const bf16x8*)(Bb + j * 512);
        #pragma unroll
        for (int i = 0; i < 10; i++) {
            bf16x8 af = *(const bf16x8*)(Ab + i * 512);
            #pragma unroll
            for (int j = 0; j < 4; j++)
                MFMA16(acc[i][j], af, bfr[j]);
        }
    };

    stage_full(0);
    stage_full(1);

    int cb = 0, sb = 2;
    for (int tt = 0; tt < 31; ++tt) {
        VMW(6);
        __builtin_amdgcn_s_barrier();
        asm volatile("" ::: "memory");
        const bool st = (tt < 30);
        char* ab = asb + sb * 40960 + wave * 1024;
        char* bb = bsb + sb * 8192  + wave * 1024;
        const bf16_t* Ab = As + cb * 20480 + aoff;
        const bf16_t* Bb = Bs + cb * 4096  + boff;

        bf16x8 bq[4], aq[4];

        #pragma unroll
        for (int j = 0; j < 4; j++) bq[j] = *(const bf16x8*)(Bb + j * 512);
        #pragma unroll
        for (int i = 0; i < 4; i++) aq[i] = *(const bf16x8*)(Ab + i * 512);
        if (st) {
            __builtin_amdgcn_global_load_lds(AS1(pA0), AS3(ab),        16, 0, 0);
            __builtin_amdgcn_global_load_lds(AS1(pA1), AS3(ab + 8192), 16, 0, 0);
        }
        __builtin_amdgcn_s_barrier();
        asm volatile("s_waitcnt lgkmcnt(0)" ::: "memory");
        __builtin_amdgcn_sched_barrier(0);
        __builtin_amdgcn_s_setprio(1);
        #pragma unroll
        for (int i = 0; i < 4; i++)
            #pragma unroll
            for (int j = 0; j < 4; j++)
                MFMA16(acc[i][j], aq[i], bq[j]);
        __builtin_amdgcn_s_setprio(0);

        #pragma unroll
        for (int i = 0; i < 3; i++) aq[i] = *(const bf16x8*)(Ab + (4 + i) * 512);
        if (st) {
            __builtin_amdgcn_global_load_lds(AS1(pA2), AS3(ab + 16384), 16, 0, 0);
            __builtin_amdgcn_global_load_lds(AS1(pA3), AS3(ab + 24576), 16, 0, 0);
        }
        __builtin_amdgcn_s_barrier();
        asm volatile("s_waitcnt lgkmcnt(0)" ::: "memory");
        __builtin_amdgcn_sched_barrier(0);
        __builtin_amdgcn_s_setprio(1);
        #pragma unroll
        for (int i = 0; i < 3; i++)
            #pragma unroll
            for (int j = 0; j < 4; j++)
                MFMA16(acc[4 + i][j], aq[i], bq[j]);
        __builtin_amdgcn_s_setprio(0);

        #pragma unroll
        for (int i = 0; i < 3; i++) aq[i] = *(const bf16x8*)(Ab + (7 + i) * 512);
        if (st) {
            __builtin_amdgcn_global_load_lds(AS1(pA4), AS3(ab + 32768), 16, 0, 0);
            __builtin_amdgcn_global_load_lds(AS1(pB0), AS3(bb),         16, 0, 0);
        }
        __builtin_amdgcn_s_barrier();
        asm volatile("s_waitcnt lgkmcnt(0)" ::: "memory");
        __builtin_amdgcn_sched_barrier(0);
        __builtin_amdgcn_s_setprio(1);
        #pragma unroll
        for (int i = 0; i < 3; i++)
            #pragma unroll
            for (int j = 0; j < 4; j++)
                MFMA16(acc[7 + i][j], aq[i], bq[j]);
        __builtin_amdgcn_s_setprio(0);

        if (st) {
            pA0 += 32; pA1 += 32; pA2 += 32; pA3 += 32; pA4 += 32; pB0 += 32;
            sb = (sb == 2) ? 0 : sb + 1;
        }
        cb = (cb == 2) ? 0 : cb + 1;
    }
    VMW(0);
    __builtin_amdgcn_s_barrier();
    asm volatile("" ::: "memory");
    compute_full(cb);

    const float* bias = bias_all + e * 1024;
    const int cobase = (ntile & 3) * 128 + wn * 64 + (lane & 15);
    float bv[4];
    #pragma unroll
    for (int j = 0; j < 4; j++) bv[j] = bias[cobase + j * 16];
    const int rbase = mtile * 640 + wm * 160 + (lane >> 4) * 4;
    #pragma unroll
    for (int i = 0; i < 10; i++) {
        #pragma unroll
        for (int r = 0; r < 4; r++) {
            int row = rbase + i * 16 + r;
            if (row < N_NODES) {
                bf16_t* cp = h1 + ((size_t)e * N_NODES + row) * DIM + cobase;
                #pragma unroll
                for (int j = 0; j < 4; j++) {
                    float v = fmaxf(acc[i][j][r] + bv[j], 0.f);
                    cp[j * 16] = (bf16_t)v;
                }
            }
        }
    }
}

// ---------------- layer-2 GEMM: compact jobs + pipelined K-loop (r14-proven) ---------
__global__ __launch_bounds__(256)
void gemm2_kernel(const bf16_t* __restrict__ A,
                  const bf16_t* __restrict__ Bt,
                  const float* __restrict__ bias_all,
                  float* __restrict__ out,
                  const int* __restrict__ lists,
                  const int* __restrict__ ecnt,
                  const int* __restrict__ jobs,
                  const float* __restrict__ top_val) {
    __shared__ __align__(16) bf16_t As[3 * 128 * 32];
    __shared__ __align__(16) bf16_t Bs[3 * 128 * 32];

    const int t = threadIdx.x;
    const int lane = t & 63;
    const int wave = t >> 6;
    const int wm = wave >> 1;
    const int wn = wave & 1;
    const int r0 = t >> 2;
    const int rot = (t >> 3) & 3;
    const int cgl = ((t & 3) - rot) & 3;
    const int cpr = lane >> 4;
    const int rfr = lane & 15;
    char* asb = (char*)&As[0];
    char* bsb = (char*)&Bs[0];
    const int wb = wave * 1024;

    const int total = jobs[4] * 4;

    for (int j = blockIdx.x; j < total; j += gridDim.x) {
        const int byt = j >> 2;
        const int bx = j & 3;
        const int e = (byt >= jobs[1]) + (byt >= jobs[2]) + (byt >= jobs[3]);
        const int by = byt - jobs[e];
        const int cnt = ecnt[e];
        const int cmax = max(cnt, 1);

        int i0 = by * 128 + r0;
        int i1 = i0 + 64;
        int arow0 = lists[e * N_NODES + min(i0, cmax - 1)];
        int arow1 = lists[e * N_NODES + min(i1, cmax - 1)];
        arow0 = min(max(arow0, 0), N_NODES - 1);
        arow1 = min(max(arow1, 0), N_NODES - 1);
        const bf16_t* Bte = Bt + (size_t)(e * 2 + 1) * DIM * K1;
        const bf16_t* aptr0 = A + (size_t)arow0 * K1 + cgl * 8;
        const bf16_t* aptr1 = A + (size_t)arow1 * K1 + cgl * 8;
        const bf16_t* bptr0 = Bte + (size_t)(bx * 128 + r0) * K1 + cgl * 8;
        const bf16_t* bptr1 = bptr0 + (size_t)64 * K1;

        f32x4 acc[4][4] = {};

        auto stage = [&](int bu) {
            char* ab = asb + bu * 8192 + wb;
            char* bb = bsb + bu * 8192 + wb;
            __builtin_amdgcn_global_load_lds(AS1(aptr0), AS3(ab),        16, 0, 0);
            __builtin_amdgcn_global_load_lds(AS1(aptr1), AS3(ab + 4096), 16, 0, 0);
            __builtin_amdgcn_global_load_lds(AS1(bptr0), AS3(bb),        16, 0, 0);
            __builtin_amdgcn_global_load_lds(AS1(bptr1), AS3(bb + 4096), 16, 0, 0);
            aptr0 += 32; aptr1 += 32; bptr0 += 32; bptr1 += 32;
        };

        auto compute = [&](int bu) {
            const bf16_t* Ab = As + bu * 4096;
            const bf16_t* Bb = Bs + bu * 4096;
            bf16x8 af[4], bfr[4];
            #pragma unroll
            for (int i = 0; i < 4; i++) {
                int r_full = wm * 64 + i * 16 + rfr;
                int p = (cpr + (r_full >> 1)) & 3;
                af[i] = *(const bf16x8*)(Ab + r_full * 32 + p * 8);
            }
            #pragma unroll
            for (int jj = 0; jj < 4; jj++) {
                int r_full = wn * 64 + jj * 16 + rfr;
                int p = (cpr + (r_full >> 1)) & 3;
                bfr[jj] = *(const bf16x8*)(Bb + r_full * 32 + p * 8);
            }
            #pragma unroll
            for (int i = 0; i < 4; i++)
                #pragma unroll
                for (int jj = 0; jj < 4; jj++)
                    MFMA16(acc[i][jj], af[i], bfr[jj]);
        };

        __builtin_amdgcn_s_barrier();
        asm volatile("" ::: "memory");

        stage(0);
        stage(1);
        int cb = 0, sb = 2;
        for (int tt = 0; tt < 31; ++tt) {
            VMW(4);
            __builtin_amdgcn_s_barrier();
            asm volatile("" ::: "memory");
            if (tt < 30) {
                stage(sb);
                sb = (sb == 2) ? 0 : sb + 1;
            }
            compute(cb);
            cb = (cb == 2) ? 0 : cb + 1;
        }
        VMW(0);
        __builtin_amdgcn_s_barrier();
        asm volatile("" ::: "memory");
        compute(cb);

        const float* bias = bias_all + e * 1024 + DIM;
        const int cbase = bx * 128 + wn * 64 + (lane & 15);
        float bv[4];
        #pragma unroll
        for (int jj = 0; jj < 4; jj++) bv[jj] = bias[cbase + jj * 16];
        #pragma unroll
        for (int i = 0; i < 4; i++) {
            #pragma unroll
            for (int r = 0; r < 4; r++) {
                int row = by * 128 + wm * 64 + i * 16 + (lane >> 4) * 4 + r;
                if (row < cnt) {
                    int node = lists[e * N_NODES + row];
                    float tv = top_val[node];
                    float* cp = out + (size_t)node * DIM + cbase;
                    #pragma unroll
                    for (int jj = 0; jj < 4; jj++) {
                        float v = fmaxf(acc[i][jj][r] + bv[jj], 0.f);
                        cp[jj * 16] = v * tv;
                    }
                }
            }
        }
    }
}

extern "C" void kernel_launch(void* const* d_in, const int* in_sizes, int n_in,
                              void* d_out, int out_size, void* d_ws, size_t ws_size,
                              hipStream_t stream) {
    const float* x       = (const float*)d_in[0];
    const int*   edge    = (const int*)d_in[1];
    const float* gw      = (const float*)d_in[2];
    const float* gb      = (const float*)d_in[3];
    const float* w_self  = (const float*)d_in[4];
    const float* w_neigh = (const float*)d_in[5];
    const float* b_exp   = (const float*)d_in[6];
    float* out = (float*)d_out;

    char* p = (char*)d_ws;
    auto alloc = [&](size_t bytes) {
        char* r = p;
        p += (bytes + 255) & ~(size_t)255;
        return r;
    };
    bf16_t* Bt      = (bf16_t*)alloc((size_t)8 * DIM * K1 * 2);
    bf16_t* acat    = (bf16_t*)alloc((size_t)N_NODES * K1 * 2);
    bf16_t* h1      = (bf16_t*)alloc((size_t)NEXP * N_NODES * DIM * 2);
    int*    deg     = (int*)alloc((size_t)N_NODES * 4);
    int*    offs    = (int*)alloc((size_t)(N_NODES + 1) * 4);
    int*    cursor  = (int*)alloc((size_t)N_NODES * 4);
    int*    csr     = (int*)alloc((size_t)N_EDGES * 4);
    int*    top_idx = (int*)alloc((size_t)N_NODES * 4);
    float*  top_val = (float*)alloc((size_t)N_NODES * 4);
    int*    ecnt    = (int*)alloc(256);
    int*    lists   = (int*)alloc((size_t)NEXP * N_NODES * 4);
    int*    jobs    = ecnt + 8;

    const int* srcE = edge;
    const int* dstE = edge + N_EDGES;

    gate_kernel<<<N_NODES / 4, 256, 0, stream>>>(x, gw, gb, top_idx, top_val, acat, deg, ecnt);
    bucket_deg_kernel<<<N_EDGES / 256, 256, 0, stream>>>(top_idx, ecnt, lists, dstE, deg);
    scan_kernel<<<1, 1024, 0, stream>>>(deg, offs, cursor, ecnt, jobs);
    fill_wtrans_kernel<<<625 + 4096, 256, 0, stream>>>(srcE, dstE, cursor, csr, w_neigh, w_self, Bt);
    agg1_kernel<<<N_NODES / 4, 256, 0, stream>>>(offs, csr, acat);
    gemm_l1_kernel<<<256, 512, 0, stream>>>(acat, Bt, b_exp, h1);
    agg2_kernel<<<N_NODES / 4, 256, 0, stream>>>(offs, csr, top_idx, h1, acat);
    gemm2_kernel<<<512, 256, 0, stream>>>(acat, Bt, b_exp, out, lists, ecnt, jobs, top_val);
}